// Round 8
// baseline (798.278 us; speedup 1.0000x reference)
//
#include <hip/hip_runtime.h>

#define NPTS 2048
#define TOPK 32
#define RPB  8   // rows per block in phase 1

typedef float v2f __attribute__((ext_vector_type(2)));
typedef unsigned int u32;
typedef u32 v2u __attribute__((ext_vector_type(2)));
typedef unsigned long long u64;

// ---------- helpers ----------
static __device__ __forceinline__ u32 umin32(u32 a, u32 b) { return b < a ? b : a; }
static __device__ __forceinline__ u64 umin64(u64 a, u64 b) { return b < a ? b : a; }

template <int CTRL>
static __device__ __forceinline__ u32 dpp_min(u32 m) {
  return umin32(m, (u32)__builtin_amdgcn_mov_dpp((int)m, CTRL, 0xF, 0xF, true));
}
static __device__ __forceinline__ u32 x16_min(u32 m) {
#if __has_builtin(__builtin_amdgcn_permlane16_swap)
  auto r = __builtin_amdgcn_permlane16_swap((int)m, (int)m, false, false);
  return umin32(m, umin32((u32)r[0], (u32)r[1]));
#else
  return umin32(m, (u32)__builtin_amdgcn_ds_swizzle((int)m, 0x401F));
#endif
}
static __device__ __forceinline__ u32 x32_min(u32 m) {
#if __has_builtin(__builtin_amdgcn_permlane32_swap)
  auto r = __builtin_amdgcn_permlane32_swap((int)m, (int)m, false, false);
  return umin32(m, umin32((u32)r[0], (u32)r[1]));
#else
  return umin32(m, (u32)__shfl_xor((int)m, 32, 64));
#endif
}
static __device__ __forceinline__ u32 sext_bit(u32 mask, int c) {
#if __has_builtin(__builtin_amdgcn_sbfe)
  return (u32)__builtin_amdgcn_sbfe((int)mask, c, 1);
#else
  return (u32)(((int)(mask << (31 - c))) >> 31);
#endif
}

template <int CTRL>
static __device__ __forceinline__ u64 dpp_min64(u64 k) {
  unsigned lo = (unsigned)k, hi = (unsigned)(k >> 32);
  unsigned olo = (unsigned)__builtin_amdgcn_mov_dpp((int)lo, CTRL, 0xF, 0xF, true);
  unsigned ohi = (unsigned)__builtin_amdgcn_mov_dpp((int)hi, CTRL, 0xF, 0xF, true);
  return umin64(k, ((u64)ohi << 32) | olo);
}
static __device__ __forceinline__ u64 x16_min64(u64 k) {
  unsigned lo = (unsigned)k, hi = (unsigned)(k >> 32);
#if __has_builtin(__builtin_amdgcn_permlane16_swap)
  auto rlo = __builtin_amdgcn_permlane16_swap(lo, lo, false, false);
  auto rhi = __builtin_amdgcn_permlane16_swap(hi, hi, false, false);
  u64 a = ((u64)rhi[0] << 32) | rlo[0];
  u64 b = ((u64)rhi[1] << 32) | rlo[1];
  return umin64(k, umin64(a, b));
#else
  unsigned olo = (unsigned)__builtin_amdgcn_ds_swizzle((int)lo, 0x401F);
  unsigned ohi = (unsigned)__builtin_amdgcn_ds_swizzle((int)hi, 0x401F);
  return umin64(k, ((u64)ohi << 32) | olo);
#endif
}
static __device__ __forceinline__ u64 x32_min64(u64 k) {
  unsigned lo = (unsigned)k, hi = (unsigned)(k >> 32);
#if __has_builtin(__builtin_amdgcn_permlane32_swap)
  auto rlo = __builtin_amdgcn_permlane32_swap(lo, lo, false, false);
  auto rhi = __builtin_amdgcn_permlane32_swap(hi, hi, false, false);
  u64 a = ((u64)rhi[0] << 32) | rlo[0];
  u64 b = ((u64)rhi[1] << 32) | rlo[1];
  return umin64(k, umin64(a, b));
#else
  unsigned olo = (unsigned)__shfl_xor((int)lo, 32, 64);
  unsigned ohi = (unsigned)__shfl_xor((int)hi, 32, 64);
  return umin64(k, ((u64)ohi << 32) | olo);
#endif
}
static __device__ __forceinline__ u64 wave_min_u64(u64 k) {
  k = dpp_min64<0xB1>(k);
  k = dpp_min64<0x4E>(k);
  k = dpp_min64<0x141>(k);
  k = dpp_min64<0x140>(k);
  k = x16_min64(k);
  k = x32_min64(k);
  return k;  // wave-uniform
}

#define FOR16(M) M(0) M(1) M(2) M(3) M(4) M(5) M(6) M(7) \
                 M(8) M(9) M(10) M(11) M(12) M(13) M(14) M(15)

// Lane's 32 target columns in NAMED registers, as float2 pairs.
#define LOADP(h) \
  v2f TX##h, TY##h, TZ##h, TQ##h; \
  { float x0 = tb[6*h+0], y0 = tb[6*h+1], z0 = tb[6*h+2]; \
    float x1 = tb[6*h+3], y1 = tb[6*h+4], z1 = tb[6*h+5]; \
    TX##h = (v2f){x0, x1}; TY##h = (v2f){y0, y1}; TZ##h = (v2f){z0, z1}; \
    TQ##h = (v2f){x0*x0 + y0*y0 + z0*z0, x1*x1 + y1*y1 + z1*z1}; }

// ---------- phase 1: exact per-row sorted top-32, incremental tree ----------
#define DISTK(h) u64 KA##h, KB##h; { \
  v2f dot = __builtin_elementwise_fma(TX##h, Xv, \
              __builtin_elementwise_fma(TY##h, Yv, TZ##h * Zv)); \
  v2f dd  = __builtin_elementwise_fma(m2v, dot, TQ##h); \
  v2f d2  = Qv + dd; \
  float c0 = fmaxf(d2.x, 1e-12f), c1 = fmaxf(d2.y, 1e-12f); \
  KA##h = ((u64)(u32)__float_as_int(c0) << 32) | (u32)(base + 2*(h)); \
  KB##h = ((u64)(u32)__float_as_int(c1) << 32) | (u32)(base + 2*(h) + 1); }

#define G4(a, b, c, d) umin64(umin64(a, b), umin64(c, d))
#define ZG(c, KV, RL) case (c): KV = own ? ~0ULL : KV; goto RL;

__global__ __launch_bounds__(64, 2) void emd_topk_kernel(
    const float* __restrict__ pred, const float* __restrict__ target,
    u64* __restrict__ lists) {
  const int blk = blockIdx.x;
  const int b  = blk / (NPTS / RPB);
  const int r0 = (blk % (NPTS / RPB)) * RPB;
  const int lane = threadIdx.x;
  const float* p = pred + (size_t)b * NPTS * 3;
  const float* t = target + (size_t)b * NPTS * 3;

  const float* tb = t + (size_t)lane * 32 * 3;
  FOR16(LOADP)
  const int base = lane << 5;
  const v2f m2v = {-2.f, -2.f};

#pragma unroll 1
  for (int rr = 0; rr < RPB; ++rr) {
    const int i = r0 + rr;
    const float X = p[3 * i], Y = p[3 * i + 1], Z = p[3 * i + 2];
    const float Q = fmaf(X, X, fmaf(Y, Y, Z * Z));
    const v2f Xv = {X, X}, Yv = {Y, Y}, Zv = {Z, Z}, Qv = {Q, Q};
    FOR16(DISTK)

    // Cached tournament tree: 8 groups of 4 leaves + upper levels.
    u64 g0 = G4(KA0, KB0, KA1, KB1),   g1 = G4(KA2, KB2, KA3, KB3);
    u64 g2 = G4(KA4, KB4, KA5, KB5),   g3 = G4(KA6, KB6, KA7, KB7);
    u64 g4 = G4(KA8, KB8, KA9, KB9),   g5 = G4(KA10, KB10, KA11, KB11);
    u64 g6 = G4(KA12, KB12, KA13, KB13), g7 = G4(KA14, KB14, KA15, KB15);
    u64 h0 = umin64(g0, g1), h1 = umin64(g2, g3);
    u64 h2 = umin64(g4, g5), h3 = umin64(g6, g7);
    u64 q0 = umin64(h0, h1), q1 = umin64(h2, h3);
    u64 root = umin64(q0, q1);

    u64* out = lists + ((size_t)b * NPTS + i) * TOPK;
#pragma unroll 1
    for (int e = 0; e < TOPK; ++e) {
      u64 m = wave_min_u64(root);
      if (lane == 0) out[e] = m;
      if (e == TOPK - 1) break;
      const u32 col = (u32)m & (u32)(NPTS - 1);  // wave-uniform
      const bool own = (lane == (int)(col >> 5));
      const u32 k5 = col & 31u;
      // Zero the winning leaf, recompute only its path to root.
      switch (k5) {
        ZG(0,  KA0,  R0) ZG(1,  KB0,  R0) ZG(2,  KA1,  R0) ZG(3,  KB1,  R0)
        ZG(4,  KA2,  R1) ZG(5,  KB2,  R1) ZG(6,  KA3,  R1) ZG(7,  KB3,  R1)
        ZG(8,  KA4,  R2) ZG(9,  KB4,  R2) ZG(10, KA5,  R2) ZG(11, KB5,  R2)
        ZG(12, KA6,  R3) ZG(13, KB6,  R3) ZG(14, KA7,  R3) ZG(15, KB7,  R3)
        ZG(16, KA8,  R4) ZG(17, KB8,  R4) ZG(18, KA9,  R4) ZG(19, KB9,  R4)
        ZG(20, KA10, R5) ZG(21, KB10, R5) ZG(22, KA11, R5) ZG(23, KB11, R5)
        ZG(24, KA12, R6) ZG(25, KB12, R6) ZG(26, KA13, R6) ZG(27, KB13, R6)
        ZG(28, KA14, R7) ZG(29, KB14, R7) ZG(30, KA15, R7) ZG(31, KB15, R7)
        default: __builtin_unreachable();
      }
      R0: g0 = G4(KA0, KB0, KA1, KB1);     h0 = umin64(g0, g1); q0 = umin64(h0, h1); root = umin64(q0, q1); continue;
      R1: g1 = G4(KA2, KB2, KA3, KB3);     h0 = umin64(g0, g1); q0 = umin64(h0, h1); root = umin64(q0, q1); continue;
      R2: g2 = G4(KA4, KB4, KA5, KB5);     h1 = umin64(g2, g3); q0 = umin64(h0, h1); root = umin64(q0, q1); continue;
      R3: g3 = G4(KA6, KB6, KA7, KB7);     h1 = umin64(g2, g3); q0 = umin64(h0, h1); root = umin64(q0, q1); continue;
      R4: g4 = G4(KA8, KB8, KA9, KB9);     h2 = umin64(g4, g5); q1 = umin64(h2, h3); root = umin64(q0, q1); continue;
      R5: g5 = G4(KA10, KB10, KA11, KB11); h2 = umin64(g4, g5); q1 = umin64(h2, h3); root = umin64(q0, q1); continue;
      R6: g6 = G4(KA12, KB12, KA13, KB13); h3 = umin64(g6, g7); q1 = umin64(h2, h3); root = umin64(q0, q1); continue;
      R7: g7 = G4(KA14, KB14, KA15, KB15); h3 = umin64(g6, g7); q1 = umin64(h2, h3); root = umin64(q0, q1); continue;
    }
  }
}

// ---------- phase 2: sequential greedy, stale-probe pipelined ----------
// Out-of-line fallback keeps the hot loop I-cache-resident.
__device__ __attribute__((noinline)) u64 fallback_min(
    const float4* tt, float X, float Y, float Z, float Q,
    u32 usedmask, int lane) {
  u64 best = ~0ULL;
  for (int k = 0; k < 32; ++k) {
    float4 c4 = tt[(k << 6) | (lane ^ k)];
    float dot = fmaf(c4.x, X, fmaf(c4.y, Y, c4.z * Z));
    float d2 = Q + fmaf(-2.f, dot, c4.w);
    d2 = fmaxf(d2, 1e-12f);
    u64 key = ((u64)(u32)__float_as_int(d2) << 32) | (u32)((lane << 5) + k);
    if ((usedmask >> k) & 1u) key = ~0ULL;
    best = umin64(best, key);
  }
  return wave_min_u64(best);
}

// Probe for row r issued 4 rows early with a stale mask; exactness restored
// by vetoing the last 3 winners: U_r = U_{r-4} + {w_{r-1}, w_{r-2}, w_{r-3}}.
#define RESOLVE(CR, PR, ROW) { \
    u32 cc = (u32)(CR) & (u32)(NPTS - 1); \
    u64 freebl = __ballot((((PR) >> (cc & 31u)) & 1u) == 0u); \
    u64 badbl  = __ballot(cc == w1) | __ballot(cc == w2) | __ballot(cc == w3); \
    u64 bl = freebl & ~badbl; \
    u32 cs, vhi; \
    if (bl != 0) { \
      int R = __ffsll(bl) - 1; \
      cs  = (u32)__builtin_amdgcn_readlane((int)(u32)(CR), R) & (u32)(NPTS - 1); \
      vhi = (u32)__builtin_amdgcn_readlane((int)(u32)((CR) >> 32), R); \
    } else { \
      float X = p[3 * (ROW)], Y = p[3 * (ROW) + 1], Z = p[3 * (ROW) + 2]; \
      float Q = fmaf(X, X, fmaf(Y, Y, Z * Z)); \
      u64 m = fallback_min((const float4*)tt, X, Y, Z, Q, usedmask, lane); \
      cs  = (u32)m & (u32)(NPTS - 1); \
      vhi = (u32)(m >> 32); \
    } \
    usedmask |= (lane == (int)(cs >> 5)) ? (1u << (cs & 31u)) : 0u; \
    sum += sqrtf(__uint_as_float(vhi)); \
    w3 = w2; w2 = w1; w1 = cs; \
  }

#define ISSUE(PR, CS) { \
    u32 qc = (u32)(CS) & (u32)(NPTS - 1); \
    PR = (u32)__builtin_amdgcn_ds_bpermute((int)((qc >> 5) << 2), (int)usedmask); }

#define RELOAD(CR, ROW) { \
    int rr_ = (ROW) < NPTS ? (ROW) : (NPTS - 1); \
    CR = L[(size_t)rr_ * TOPK + li]; }

#define STEP(J, CR, PR, CN, I) \
    RESOLVE(CR, PR, (I) + (J)) \
    ISSUE(PR, CN) \
    RELOAD(CR, (I) + (J) + 8)

__global__ __launch_bounds__(64, 1) void emd_seq_kernel(
    const float* __restrict__ pred, const float* __restrict__ target,
    const u64* __restrict__ lists, float* __restrict__ batch_sums) {
  const int b = blockIdx.x, lane = threadIdx.x;
  const float* p = pred + (size_t)b * NPTS * 3;
  const float* t = target + (size_t)b * NPTS * 3;

  // Fallback targets: column c at tt[((c&31)<<6) | ((c>>5) ^ (c&31))]
  // (XOR swizzle: staging writes spread 4-way instead of 32-way).
  __shared__ float4 tt[NPTS];
  for (int j = lane; j < NPTS; j += 64) {
    float x = t[3 * j], y = t[3 * j + 1], z = t[3 * j + 2];
    tt[((j & 31) << 6) | ((j >> 5) ^ (j & 31))] =
        make_float4(x, y, z, fmaf(x, x, fmaf(y, y, z * z)));
  }
  __syncthreads();

  const u64* L = lists + (size_t)b * NPTS * TOPK;
  const int li = lane & (TOPK - 1);
  u32 usedmask = 0;
  u32 w1 = 0xFFFFFFFFu, w2 = 0xFFFFFFFFu, w3 = 0xFFFFFFFFu;
  float sum = 0.f;

  // 8-deep candidate prefetch; 4-deep probe pipeline.
  u64 C0 = L[0 * TOPK + li], C1 = L[1 * TOPK + li];
  u64 C2 = L[2 * TOPK + li], C3 = L[3 * TOPK + li];
  u64 C4 = L[4 * TOPK + li], C5 = L[5 * TOPK + li];
  u64 C6 = L[6 * TOPK + li], C7 = L[7 * TOPK + li];
  u32 P0, P1, P2, P3;
  ISSUE(P0, C0) ISSUE(P1, C1) ISSUE(P2, C2) ISSUE(P3, C3)

#pragma unroll 1
  for (int i = 0; i < NPTS; i += 8) {
    STEP(0, C0, P0, C4, i)
    STEP(1, C1, P1, C5, i)
    STEP(2, C2, P2, C6, i)
    STEP(3, C3, P3, C7, i)
    STEP(4, C4, P0, C0, i)
    STEP(5, C5, P1, C1, i)
    STEP(6, C6, P2, C2, i)
    STEP(7, C7, P3, C3, i)
  }
  if (lane == 0) batch_sums[b] = sum;
}

// ---------- legacy single-kernel path (round-5, proven; ws-too-small) ----------
#define DECLRU(h) v2u RU##h;
#define DIST(h) { \
  v2f dot = __builtin_elementwise_fma(TX##h, Xv, \
              __builtin_elementwise_fma(TY##h, Yv, TZ##h * Zv)); \
  v2f dd  = __builtin_elementwise_fma(m2v, dot, TQ##h); \
  v2f d2  = Qv + dd; \
  RU##h = (v2u){(u32)__float_as_int(d2.x), (u32)__float_as_int(d2.y)}; }
#define TOUR(h, c) { \
  u32 u0 = RU##h.x | sext_bit(usedmask, 2*h); \
  u32 u1 = RU##h.y | sext_bit(usedmask, 2*h + 1); \
  u32 pu = umin32(u0, u1); \
  u32 pk = (u1 < u0) ? (u32)(2*h + 1) : (u32)(2*h); \
  if (pu < bc##c) { bc##c = pu; kc##c = pk; } }

__global__ __launch_bounds__(64, 1) void emd_greedy_kernel(
    const float* __restrict__ pred, const float* __restrict__ target,
    float* __restrict__ batch_sums) {
  const int b = blockIdx.x, lane = threadIdx.x;
  const float* p = pred + (size_t)b * NPTS * 3;
  const float* t = target + (size_t)b * NPTS * 3;
  __shared__ float4 pp[NPTS + 2];
  for (int i = lane; i < NPTS; i += 64) {
    float x = p[3 * i], y = p[3 * i + 1], z = p[3 * i + 2];
    pp[i] = make_float4(x, y, z, x * x + y * y + z * z);
  }
  if (lane < 2) pp[NPTS + lane] = make_float4(0.f, 0.f, 0.f, 0.f);
  const float* tb = t + (size_t)lane * 32 * 3;
  FOR16(LOADP)
  FOR16(DECLRU)
  u32 usedmask = 0;
  float sum = 0.f;
  __syncthreads();
  const v2f m2v = {-2.f, -2.f};
  v2f Xv, Yv, Zv, Qv;
  {
    float4 A = pp[0];
    Xv = (v2f){A.x, A.x}; Yv = (v2f){A.y, A.y};
    Zv = (v2f){A.z, A.z}; Qv = (v2f){A.w, A.w};
    FOR16(DIST)
  }
  for (int i = 0; i < NPTS; ++i) {
    float4 An = pp[i + 1];
    u32 bc0 = ~0u, bc1 = ~0u, bc2 = ~0u, bc3 = ~0u;
    u32 kc0 = 0, kc1 = 0, kc2 = 0, kc3 = 0;
    TOUR(0, 0)  TOUR(1, 0)  TOUR(2, 0)  TOUR(3, 0)
    TOUR(4, 1)  TOUR(5, 1)  TOUR(6, 1)  TOUR(7, 1)
    TOUR(8, 2)  TOUR(9, 2)  TOUR(10, 2) TOUR(11, 2)
    TOUR(12, 3) TOUR(13, 3) TOUR(14, 3) TOUR(15, 3)
    bool s01 = bc1 < bc0; u32 v01 = s01 ? bc1 : bc0; u32 i01 = s01 ? kc1 : kc0;
    bool s23 = bc3 < bc2; u32 v23 = s23 ? bc3 : bc2; u32 i23 = s23 ? kc3 : kc2;
    bool sf  = v23 < v01; u32 bu  = sf ? v23 : v01; u32 bk  = sf ? i23 : i01;
    Xv = (v2f){An.x, An.x}; Yv = (v2f){An.y, An.y};
    Zv = (v2f){An.z, An.z}; Qv = (v2f){An.w, An.w};
    FOR16(DIST)
    u32 m = bu;
    m = dpp_min<0xB1>(m); m = dpp_min<0x4E>(m);
    m = dpp_min<0x141>(m); m = dpp_min<0x140>(m);
    m = x16_min(m); m = x32_min(m);
    u64 mk = __ballot(bu == m);
    int first = __ffsll(mk) - 1;
    usedmask |= (lane == first) ? (1u << bk) : 0u;
    sum += sqrtf(fmaxf(__uint_as_float(m), 1e-12f));
  }
  if (lane == 0) batch_sums[b] = sum;
}

// ---------- finalize ----------
__global__ void emd_finalize_kernel(const float* __restrict__ batch_sums,
                                    float* __restrict__ out, int B) {
  float acc = 0.f;
  for (int b = 0; b < B; ++b) acc += batch_sums[b] / (float)NPTS;
  out[0] = acc / (float)B;
}

extern "C" void kernel_launch(void* const* d_in, const int* in_sizes, int n_in,
                              void* d_out, int out_size, void* d_ws, size_t ws_size,
                              hipStream_t stream) {
  const float* pred   = (const float*)d_in[0];
  const float* target = (const float*)d_in[1];
  float* out = (float*)d_out;
  const int B = in_sizes[0] / (NPTS * 3);

  const size_t need = 256 + (size_t)B * NPTS * TOPK * sizeof(u64);
  if (ws_size >= need) {
    float* bs = (float*)d_ws;
    u64* lists = (u64*)((char*)d_ws + 256);
    emd_topk_kernel<<<B * (NPTS / RPB), 64, 0, stream>>>(pred, target, lists);
    emd_seq_kernel<<<B, 64, 0, stream>>>(pred, target, lists, bs);
    emd_finalize_kernel<<<1, 1, 0, stream>>>(bs, out, B);
  } else {
    float* bs = (float*)d_ws;
    emd_greedy_kernel<<<B, 64, 0, stream>>>(pred, target, bs);
    emd_finalize_kernel<<<1, 1, 0, stream>>>(bs, out, B);
  }
}

// Round 9
// 796.075 us; speedup vs baseline: 1.0028x; 1.0028x over previous
//
#include <hip/hip_runtime.h>

#define NPTS 2048
#define TOPK 32
#define RPB  8   // rows per block in phase 1

typedef float v2f __attribute__((ext_vector_type(2)));
typedef unsigned int u32;
typedef u32 v2u __attribute__((ext_vector_type(2)));
typedef unsigned long long u64;

// ---------- helpers ----------
static __device__ __forceinline__ u32 umin32(u32 a, u32 b) { return b < a ? b : a; }
static __device__ __forceinline__ u64 umin64(u64 a, u64 b) { return b < a ? b : a; }

template <int CTRL>
static __device__ __forceinline__ u32 dpp_min(u32 m) {
  return umin32(m, (u32)__builtin_amdgcn_mov_dpp((int)m, CTRL, 0xF, 0xF, true));
}
static __device__ __forceinline__ u32 x16_min(u32 m) {
#if __has_builtin(__builtin_amdgcn_permlane16_swap)
  auto r = __builtin_amdgcn_permlane16_swap((int)m, (int)m, false, false);
  return umin32(m, umin32((u32)r[0], (u32)r[1]));
#else
  return umin32(m, (u32)__builtin_amdgcn_ds_swizzle((int)m, 0x401F));
#endif
}
static __device__ __forceinline__ u32 x32_min(u32 m) {
#if __has_builtin(__builtin_amdgcn_permlane32_swap)
  auto r = __builtin_amdgcn_permlane32_swap((int)m, (int)m, false, false);
  return umin32(m, umin32((u32)r[0], (u32)r[1]));
#else
  return umin32(m, (u32)__shfl_xor((int)m, 32, 64));
#endif
}
// All-VALU wave-wide u32 min (chain ~12 instructions).
static __device__ __forceinline__ u32 wave_min_u32(u32 m) {
  m = dpp_min<0xB1>(m);   // xor 1
  m = dpp_min<0x4E>(m);   // xor 2
  m = dpp_min<0x141>(m);  // half-row mirror
  m = dpp_min<0x140>(m);  // row mirror
  m = x16_min(m);
  m = x32_min(m);
  return m;  // uniform
}
static __device__ __forceinline__ u32 sext_bit(u32 mask, int c) {
#if __has_builtin(__builtin_amdgcn_sbfe)
  return (u32)__builtin_amdgcn_sbfe((int)mask, c, 1);
#else
  return (u32)(((int)(mask << (31 - c))) >> 31);
#endif
}

template <int CTRL>
static __device__ __forceinline__ u64 dpp_min64(u64 k) {
  unsigned lo = (unsigned)k, hi = (unsigned)(k >> 32);
  unsigned olo = (unsigned)__builtin_amdgcn_mov_dpp((int)lo, CTRL, 0xF, 0xF, true);
  unsigned ohi = (unsigned)__builtin_amdgcn_mov_dpp((int)hi, CTRL, 0xF, 0xF, true);
  return umin64(k, ((u64)ohi << 32) | olo);
}
static __device__ __forceinline__ u64 x16_min64(u64 k) {
  unsigned lo = (unsigned)k, hi = (unsigned)(k >> 32);
#if __has_builtin(__builtin_amdgcn_permlane16_swap)
  auto rlo = __builtin_amdgcn_permlane16_swap(lo, lo, false, false);
  auto rhi = __builtin_amdgcn_permlane16_swap(hi, hi, false, false);
  u64 a = ((u64)rhi[0] << 32) | rlo[0];
  u64 b = ((u64)rhi[1] << 32) | rlo[1];
  return umin64(k, umin64(a, b));
#else
  unsigned olo = (unsigned)__builtin_amdgcn_ds_swizzle((int)lo, 0x401F);
  unsigned ohi = (unsigned)__builtin_amdgcn_ds_swizzle((int)hi, 0x401F);
  return umin64(k, ((u64)ohi << 32) | olo);
#endif
}
static __device__ __forceinline__ u64 x32_min64(u64 k) {
  unsigned lo = (unsigned)k, hi = (unsigned)(k >> 32);
#if __has_builtin(__builtin_amdgcn_permlane32_swap)
  auto rlo = __builtin_amdgcn_permlane32_swap(lo, lo, false, false);
  auto rhi = __builtin_amdgcn_permlane32_swap(hi, hi, false, false);
  u64 a = ((u64)rhi[0] << 32) | rlo[0];
  u64 b = ((u64)rhi[1] << 32) | rlo[1];
  return umin64(k, umin64(a, b));
#else
  unsigned olo = (unsigned)__shfl_xor((int)lo, 32, 64);
  unsigned ohi = (unsigned)__shfl_xor((int)hi, 32, 64);
  return umin64(k, ((u64)ohi << 32) | olo);
#endif
}
static __device__ __forceinline__ u64 wave_min_u64(u64 k) {
  k = dpp_min64<0xB1>(k);
  k = dpp_min64<0x4E>(k);
  k = dpp_min64<0x141>(k);
  k = dpp_min64<0x140>(k);
  k = x16_min64(k);
  k = x32_min64(k);
  return k;  // wave-uniform
}

#define FOR16(M) M(0) M(1) M(2) M(3) M(4) M(5) M(6) M(7) \
                 M(8) M(9) M(10) M(11) M(12) M(13) M(14) M(15)

// Lane's 32 target columns in NAMED registers, as float2 pairs.
#define LOADP(h) \
  v2f TX##h, TY##h, TZ##h, TQ##h; \
  { float x0 = tb[6*h+0], y0 = tb[6*h+1], z0 = tb[6*h+2]; \
    float x1 = tb[6*h+3], y1 = tb[6*h+4], z1 = tb[6*h+5]; \
    TX##h = (v2f){x0, x1}; TY##h = (v2f){y0, y1}; TZ##h = (v2f){z0, z1}; \
    TQ##h = (v2f){x0*x0 + y0*y0 + z0*z0, x1*x1 + y1*y1 + z1*z1}; }

// ---------- phase 1: exact per-row sorted top-32, incremental tree ----------
#define DISTK(h) u64 KA##h, KB##h; { \
  v2f dot = __builtin_elementwise_fma(TX##h, Xv, \
              __builtin_elementwise_fma(TY##h, Yv, TZ##h * Zv)); \
  v2f dd  = __builtin_elementwise_fma(m2v, dot, TQ##h); \
  v2f d2  = Qv + dd; \
  float c0 = fmaxf(d2.x, 1e-12f), c1 = fmaxf(d2.y, 1e-12f); \
  KA##h = ((u64)(u32)__float_as_int(c0) << 32) | (u32)(base + 2*(h)); \
  KB##h = ((u64)(u32)__float_as_int(c1) << 32) | (u32)(base + 2*(h) + 1); }

#define G4(a, b, c, d) umin64(umin64(a, b), umin64(c, d))
#define ZG(c, KV, RL) case (c): KV = own ? ~0ULL : KV; goto RL;

__global__ __launch_bounds__(64, 2) void emd_topk_kernel(
    const float* __restrict__ pred, const float* __restrict__ target,
    u64* __restrict__ lists) {
  const int blk = blockIdx.x;
  const int b  = blk / (NPTS / RPB);
  const int r0 = (blk % (NPTS / RPB)) * RPB;
  const int lane = threadIdx.x;
  const float* p = pred + (size_t)b * NPTS * 3;
  const float* t = target + (size_t)b * NPTS * 3;

  const float* tb = t + (size_t)lane * 32 * 3;
  FOR16(LOADP)
  const int base = lane << 5;
  const v2f m2v = {-2.f, -2.f};

#pragma unroll 1
  for (int rr = 0; rr < RPB; ++rr) {
    const int i = r0 + rr;
    const float X = p[3 * i], Y = p[3 * i + 1], Z = p[3 * i + 2];
    const float Q = fmaf(X, X, fmaf(Y, Y, Z * Z));
    const v2f Xv = {X, X}, Yv = {Y, Y}, Zv = {Z, Z}, Qv = {Q, Q};
    FOR16(DISTK)

    // Cached tournament tree: 8 groups of 4 leaves + upper levels.
    u64 g0 = G4(KA0, KB0, KA1, KB1),   g1 = G4(KA2, KB2, KA3, KB3);
    u64 g2 = G4(KA4, KB4, KA5, KB5),   g3 = G4(KA6, KB6, KA7, KB7);
    u64 g4 = G4(KA8, KB8, KA9, KB9),   g5 = G4(KA10, KB10, KA11, KB11);
    u64 g6 = G4(KA12, KB12, KA13, KB13), g7 = G4(KA14, KB14, KA15, KB15);
    u64 h0 = umin64(g0, g1), h1 = umin64(g2, g3);
    u64 h2 = umin64(g4, g5), h3 = umin64(g6, g7);
    u64 q0 = umin64(h0, h1), q1 = umin64(h2, h3);
    u64 root = umin64(q0, q1);

    u64* out = lists + ((size_t)b * NPTS + i) * TOPK;
#pragma unroll 1
    for (int e = 0; e < TOPK; ++e) {
      u64 m = wave_min_u64(root);
      if (lane == 0) out[e] = m;
      if (e == TOPK - 1) break;
      const u32 col = (u32)m & (u32)(NPTS - 1);  // wave-uniform
      const bool own = (lane == (int)(col >> 5));
      const u32 k5 = col & 31u;
      switch (k5) {
        ZG(0,  KA0,  R0) ZG(1,  KB0,  R0) ZG(2,  KA1,  R0) ZG(3,  KB1,  R0)
        ZG(4,  KA2,  R1) ZG(5,  KB2,  R1) ZG(6,  KA3,  R1) ZG(7,  KB3,  R1)
        ZG(8,  KA4,  R2) ZG(9,  KB4,  R2) ZG(10, KA5,  R2) ZG(11, KB5,  R2)
        ZG(12, KA6,  R3) ZG(13, KB6,  R3) ZG(14, KA7,  R3) ZG(15, KB7,  R3)
        ZG(16, KA8,  R4) ZG(17, KB8,  R4) ZG(18, KA9,  R4) ZG(19, KB9,  R4)
        ZG(20, KA10, R5) ZG(21, KB10, R5) ZG(22, KA11, R5) ZG(23, KB11, R5)
        ZG(24, KA12, R6) ZG(25, KB12, R6) ZG(26, KA13, R6) ZG(27, KB13, R6)
        ZG(28, KA14, R7) ZG(29, KB14, R7) ZG(30, KA15, R7) ZG(31, KB15, R7)
        default: __builtin_unreachable();
      }
      R0: g0 = G4(KA0, KB0, KA1, KB1);     h0 = umin64(g0, g1); q0 = umin64(h0, h1); root = umin64(q0, q1); continue;
      R1: g1 = G4(KA2, KB2, KA3, KB3);     h0 = umin64(g0, g1); q0 = umin64(h0, h1); root = umin64(q0, q1); continue;
      R2: g2 = G4(KA4, KB4, KA5, KB5);     h1 = umin64(g2, g3); q0 = umin64(h0, h1); root = umin64(q0, q1); continue;
      R3: g3 = G4(KA6, KB6, KA7, KB7);     h1 = umin64(g2, g3); q0 = umin64(h0, h1); root = umin64(q0, q1); continue;
      R4: g4 = G4(KA8, KB8, KA9, KB9);     h2 = umin64(g4, g5); q1 = umin64(h2, h3); root = umin64(q0, q1); continue;
      R5: g5 = G4(KA10, KB10, KA11, KB11); h2 = umin64(g4, g5); q1 = umin64(h2, h3); root = umin64(q0, q1); continue;
      R6: g6 = G4(KA12, KB12, KA13, KB13); h3 = umin64(g6, g7); q1 = umin64(h2, h3); root = umin64(q0, q1); continue;
      R7: g7 = G4(KA14, KB14, KA15, KB15); h3 = umin64(g6, g7); q1 = umin64(h2, h3); root = umin64(q0, q1); continue;
    }
  }
}

// ---------- phase 2: sequential greedy, rank-based VALU-only resolve ----------
// Sorted list => first free candidate == min RANK among alive. rk packs
// (rank<<11)|col at reload (off-chain). Chain per row: veto-xor/min3 ->
// mask cndmask -> 12-inst wave_min_u32 -> cs. d2 readlane + usedmask
// update + sqrt-sum are off the serial chain. Probe (ds_bpermute of the
// owner lane's usedmask) issued 4 rows early; last-3-winner veto restores
// exactness: U_r = U_{r-4} + {w_{r-1},w_{r-2},w_{r-3}}.
#define RESOLVE(CR, RK, PR, ROW) { \
    u32 cc = (RK) & (u32)(NPTS - 1); \
    u32 ub = ((PR) >> (cc & 31u)) & 1u; \
    u32 m3 = umin32(umin32(cc ^ w1v, cc ^ w2v), cc ^ w3v); \
    u32 tt_ = ub ? 0u : m3; \
    u32 key = (tt_ == 0u) ? 0xFFFFFFFFu : (RK); \
    u32 km = wave_min_u32(key); \
    u32 cs, whi; \
    if (__builtin_amdgcn_readfirstlane((int)km) == -1) { \
      float X = p[3 * (ROW)], Y = p[3 * (ROW) + 1], Z = p[3 * (ROW) + 2]; \
      float Q = fmaf(X, X, fmaf(Y, Y, Z * Z)); \
      u64 mb = ~0ULL; \
      for (int k = 0; k < 32; ++k) { \
        float4 c4 = tt[(k << 6) | (lane ^ k)]; \
        float dot = fmaf(c4.x, X, fmaf(c4.y, Y, c4.z * Z)); \
        float d2 = Q + fmaf(-2.f, dot, c4.w); \
        d2 = fmaxf(d2, 1e-12f); \
        u64 kk = ((u64)(u32)__float_as_int(d2) << 32) | (u32)((lane << 5) + k); \
        if ((usedmask >> k) & 1u) kk = ~0ULL; \
        mb = umin64(mb, kk); \
      } \
      mb = wave_min_u64(mb); \
      cs = (u32)mb & (u32)(NPTS - 1); \
      whi = (u32)(mb >> 32); \
    } else { \
      cs = km & (u32)(NPTS - 1); \
      int Rs = __builtin_amdgcn_readfirstlane((int)(km >> 11)); \
      whi = (u32)__builtin_amdgcn_readlane((int)(u32)((CR) >> 32), Rs); \
    } \
    w3v = w2v; w2v = w1v; w1v = cs; \
    usedmask |= (lane == (int)(cs >> 5)) ? (1u << (cs & 31u)) : 0u; \
    sum += sqrtf(__uint_as_float(whi)); \
  }

#define ISSUE(PR, RK) { \
    u32 qc = (RK) & (u32)(NPTS - 1); \
    PR = (u32)__builtin_amdgcn_ds_bpermute((int)((qc >> 5) << 2), (int)usedmask); }

#define RELOAD(CR, RK, ROW) { \
    int rr_ = (ROW) < NPTS ? (ROW) : (NPTS - 1); \
    CR = L[(size_t)rr_ * TOPK + li]; \
    RK = ((u32)li << 11) | ((u32)(CR) & (u32)(NPTS - 1)); }

#define STEP(J, CR, RK, PR, RKN, I) \
    RESOLVE(CR, RK, PR, (I) + (J)) \
    ISSUE(PR, RKN) \
    RELOAD(CR, RK, (I) + (J) + 16)

__global__ __launch_bounds__(64, 1) void emd_seq_kernel(
    const float* __restrict__ pred, const float* __restrict__ target,
    const u64* __restrict__ lists, float* __restrict__ batch_sums) {
  const int b = blockIdx.x, lane = threadIdx.x;
  const float* p = pred + (size_t)b * NPTS * 3;
  const float* t = target + (size_t)b * NPTS * 3;

  // Fallback targets: column c at tt[((c&31)<<6) | ((c>>5) ^ (c&31))].
  __shared__ float4 tt[NPTS];
  for (int j = lane; j < NPTS; j += 64) {
    float x = t[3 * j], y = t[3 * j + 1], z = t[3 * j + 2];
    tt[((j & 31) << 6) | ((j >> 5) ^ (j & 31))] =
        make_float4(x, y, z, fmaf(x, x, fmaf(y, y, z * z)));
  }
  __syncthreads();

  const u64* L = lists + (size_t)b * NPTS * TOPK;
  const int li = lane & (TOPK - 1);
  u32 usedmask = 0;
  u32 w1v = 0x7FFFFFFFu, w2v = 0x7FFFFFFFu, w3v = 0x7FFFFFFFu;
  float sum = 0.f;

  // 16-deep candidate prefetch; 4-deep probe pipeline.
  u64 C0, C1, C2, C3, C4, C5, C6, C7, C8, C9, C10, C11, C12, C13, C14, C15;
  u32 R0_, R1_, R2_, R3_, R4_, R5_, R6_, R7_, R8_, R9_, R10_, R11_, R12_, R13_, R14_, R15_;
  RELOAD(C0, R0_, 0)   RELOAD(C1, R1_, 1)   RELOAD(C2, R2_, 2)   RELOAD(C3, R3_, 3)
  RELOAD(C4, R4_, 4)   RELOAD(C5, R5_, 5)   RELOAD(C6, R6_, 6)   RELOAD(C7, R7_, 7)
  RELOAD(C8, R8_, 8)   RELOAD(C9, R9_, 9)   RELOAD(C10, R10_, 10) RELOAD(C11, R11_, 11)
  RELOAD(C12, R12_, 12) RELOAD(C13, R13_, 13) RELOAD(C14, R14_, 14) RELOAD(C15, R15_, 15)
  u32 P0, P1, P2, P3;
  ISSUE(P0, R0_) ISSUE(P1, R1_) ISSUE(P2, R2_) ISSUE(P3, R3_)

#pragma unroll 1
  for (int i = 0; i < NPTS; i += 16) {
    STEP(0,  C0,  R0_,  P0, R4_,  i)
    STEP(1,  C1,  R1_,  P1, R5_,  i)
    STEP(2,  C2,  R2_,  P2, R6_,  i)
    STEP(3,  C3,  R3_,  P3, R7_,  i)
    STEP(4,  C4,  R4_,  P0, R8_,  i)
    STEP(5,  C5,  R5_,  P1, R9_,  i)
    STEP(6,  C6,  R6_,  P2, R10_, i)
    STEP(7,  C7,  R7_,  P3, R11_, i)
    STEP(8,  C8,  R8_,  P0, R12_, i)
    STEP(9,  C9,  R9_,  P1, R13_, i)
    STEP(10, C10, R10_, P2, R14_, i)
    STEP(11, C11, R11_, P3, R15_, i)
    STEP(12, C12, R12_, P0, R0_,  i)
    STEP(13, C13, R13_, P1, R1_,  i)
    STEP(14, C14, R14_, P2, R2_,  i)
    STEP(15, C15, R15_, P3, R3_,  i)
  }
  if (lane == 0) batch_sums[b] = sum;
}

// ---------- legacy single-kernel path (round-5, proven; ws-too-small) ----------
#define DECLRU(h) v2u RU##h;
#define DIST(h) { \
  v2f dot = __builtin_elementwise_fma(TX##h, Xv, \
              __builtin_elementwise_fma(TY##h, Yv, TZ##h * Zv)); \
  v2f dd  = __builtin_elementwise_fma(m2v, dot, TQ##h); \
  v2f d2  = Qv + dd; \
  RU##h = (v2u){(u32)__float_as_int(d2.x), (u32)__float_as_int(d2.y)}; }
#define TOUR(h, c) { \
  u32 u0 = RU##h.x | sext_bit(usedmask, 2*h); \
  u32 u1 = RU##h.y | sext_bit(usedmask, 2*h + 1); \
  u32 pu = umin32(u0, u1); \
  u32 pk = (u1 < u0) ? (u32)(2*h + 1) : (u32)(2*h); \
  if (pu < bc##c) { bc##c = pu; kc##c = pk; } }

__global__ __launch_bounds__(64, 1) void emd_greedy_kernel(
    const float* __restrict__ pred, const float* __restrict__ target,
    float* __restrict__ batch_sums) {
  const int b = blockIdx.x, lane = threadIdx.x;
  const float* p = pred + (size_t)b * NPTS * 3;
  const float* t = target + (size_t)b * NPTS * 3;
  __shared__ float4 pp[NPTS + 2];
  for (int i = lane; i < NPTS; i += 64) {
    float x = p[3 * i], y = p[3 * i + 1], z = p[3 * i + 2];
    pp[i] = make_float4(x, y, z, x * x + y * y + z * z);
  }
  if (lane < 2) pp[NPTS + lane] = make_float4(0.f, 0.f, 0.f, 0.f);
  const float* tb = t + (size_t)lane * 32 * 3;
  FOR16(LOADP)
  FOR16(DECLRU)
  u32 usedmask = 0;
  float sum = 0.f;
  __syncthreads();
  const v2f m2v = {-2.f, -2.f};
  v2f Xv, Yv, Zv, Qv;
  {
    float4 A = pp[0];
    Xv = (v2f){A.x, A.x}; Yv = (v2f){A.y, A.y};
    Zv = (v2f){A.z, A.z}; Qv = (v2f){A.w, A.w};
    FOR16(DIST)
  }
  for (int i = 0; i < NPTS; ++i) {
    float4 An = pp[i + 1];
    u32 bc0 = ~0u, bc1 = ~0u, bc2 = ~0u, bc3 = ~0u;
    u32 kc0 = 0, kc1 = 0, kc2 = 0, kc3 = 0;
    TOUR(0, 0)  TOUR(1, 0)  TOUR(2, 0)  TOUR(3, 0)
    TOUR(4, 1)  TOUR(5, 1)  TOUR(6, 1)  TOUR(7, 1)
    TOUR(8, 2)  TOUR(9, 2)  TOUR(10, 2) TOUR(11, 2)
    TOUR(12, 3) TOUR(13, 3) TOUR(14, 3) TOUR(15, 3)
    bool s01 = bc1 < bc0; u32 v01 = s01 ? bc1 : bc0; u32 i01 = s01 ? kc1 : kc0;
    bool s23 = bc3 < bc2; u32 v23 = s23 ? bc3 : bc2; u32 i23 = s23 ? kc3 : kc2;
    bool sf  = v23 < v01; u32 bu  = sf ? v23 : v01; u32 bk  = sf ? i23 : i01;
    Xv = (v2f){An.x, An.x}; Yv = (v2f){An.y, An.y};
    Zv = (v2f){An.z, An.z}; Qv = (v2f){An.w, An.w};
    FOR16(DIST)
    u32 m = bu;
    m = dpp_min<0xB1>(m); m = dpp_min<0x4E>(m);
    m = dpp_min<0x141>(m); m = dpp_min<0x140>(m);
    m = x16_min(m); m = x32_min(m);
    u64 mk = __ballot(bu == m);
    int first = __ffsll(mk) - 1;
    usedmask |= (lane == first) ? (1u << bk) : 0u;
    sum += sqrtf(fmaxf(__uint_as_float(m), 1e-12f));
  }
  if (lane == 0) batch_sums[b] = sum;
}

// ---------- finalize ----------
__global__ void emd_finalize_kernel(const float* __restrict__ batch_sums,
                                    float* __restrict__ out, int B) {
  float acc = 0.f;
  for (int b = 0; b < B; ++b) acc += batch_sums[b] / (float)NPTS;
  out[0] = acc / (float)B;
}

extern "C" void kernel_launch(void* const* d_in, const int* in_sizes, int n_in,
                              void* d_out, int out_size, void* d_ws, size_t ws_size,
                              hipStream_t stream) {
  const float* pred   = (const float*)d_in[0];
  const float* target = (const float*)d_in[1];
  float* out = (float*)d_out;
  const int B = in_sizes[0] / (NPTS * 3);

  const size_t need = 256 + (size_t)B * NPTS * TOPK * sizeof(u64);
  if (ws_size >= need) {
    float* bs = (float*)d_ws;
    u64* lists = (u64*)((char*)d_ws + 256);
    emd_topk_kernel<<<B * (NPTS / RPB), 64, 0, stream>>>(pred, target, lists);
    emd_seq_kernel<<<B, 64, 0, stream>>>(pred, target, lists, bs);
    emd_finalize_kernel<<<1, 1, 0, stream>>>(bs, out, B);
  } else {
    float* bs = (float*)d_ws;
    emd_greedy_kernel<<<B, 64, 0, stream>>>(pred, target, bs);
    emd_finalize_kernel<<<1, 1, 0, stream>>>(bs, out, B);
  }
}

// Round 10
// 758.247 us; speedup vs baseline: 1.0528x; 1.0499x over previous
//
#include <hip/hip_runtime.h>

#define NPTS 2048
#define TOPK 32
#define RPB  8   // rows per block in phase 1

typedef float v2f __attribute__((ext_vector_type(2)));
typedef unsigned int u32;
typedef u32 v2u __attribute__((ext_vector_type(2)));
typedef unsigned long long u64;

// ---------- helpers ----------
static __device__ __forceinline__ u32 umin32(u32 a, u32 b) { return b < a ? b : a; }
static __device__ __forceinline__ u64 umin64(u64 a, u64 b) { return b < a ? b : a; }

template <int CTRL>
static __device__ __forceinline__ u32 dpp_min(u32 m) {
  return umin32(m, (u32)__builtin_amdgcn_mov_dpp((int)m, CTRL, 0xF, 0xF, true));
}
static __device__ __forceinline__ u32 x16_min(u32 m) {
#if __has_builtin(__builtin_amdgcn_permlane16_swap)
  auto r = __builtin_amdgcn_permlane16_swap((int)m, (int)m, false, false);
  return umin32(m, umin32((u32)r[0], (u32)r[1]));
#else
  return umin32(m, (u32)__builtin_amdgcn_ds_swizzle((int)m, 0x401F));
#endif
}
static __device__ __forceinline__ u32 x32_min(u32 m) {
#if __has_builtin(__builtin_amdgcn_permlane32_swap)
  auto r = __builtin_amdgcn_permlane32_swap((int)m, (int)m, false, false);
  return umin32(m, umin32((u32)r[0], (u32)r[1]));
#else
  return umin32(m, (u32)__shfl_xor((int)m, 32, 64));
#endif
}
static __device__ __forceinline__ u32 sext_bit(u32 mask, int c) {
#if __has_builtin(__builtin_amdgcn_sbfe)
  return (u32)__builtin_amdgcn_sbfe((int)mask, c, 1);
#else
  return (u32)(((int)(mask << (31 - c))) >> 31);
#endif
}

template <int CTRL>
static __device__ __forceinline__ u64 dpp_min64(u64 k) {
  unsigned lo = (unsigned)k, hi = (unsigned)(k >> 32);
  unsigned olo = (unsigned)__builtin_amdgcn_mov_dpp((int)lo, CTRL, 0xF, 0xF, true);
  unsigned ohi = (unsigned)__builtin_amdgcn_mov_dpp((int)hi, CTRL, 0xF, 0xF, true);
  return umin64(k, ((u64)ohi << 32) | olo);
}
static __device__ __forceinline__ u64 x16_min64(u64 k) {
  unsigned lo = (unsigned)k, hi = (unsigned)(k >> 32);
#if __has_builtin(__builtin_amdgcn_permlane16_swap)
  auto rlo = __builtin_amdgcn_permlane16_swap(lo, lo, false, false);
  auto rhi = __builtin_amdgcn_permlane16_swap(hi, hi, false, false);
  u64 a = ((u64)rhi[0] << 32) | rlo[0];
  u64 b = ((u64)rhi[1] << 32) | rlo[1];
  return umin64(k, umin64(a, b));
#else
  unsigned olo = (unsigned)__builtin_amdgcn_ds_swizzle((int)lo, 0x401F);
  unsigned ohi = (unsigned)__builtin_amdgcn_ds_swizzle((int)hi, 0x401F);
  return umin64(k, ((u64)ohi << 32) | olo);
#endif
}
static __device__ __forceinline__ u64 x32_min64(u64 k) {
  unsigned lo = (unsigned)k, hi = (unsigned)(k >> 32);
#if __has_builtin(__builtin_amdgcn_permlane32_swap)
  auto rlo = __builtin_amdgcn_permlane32_swap(lo, lo, false, false);
  auto rhi = __builtin_amdgcn_permlane32_swap(hi, hi, false, false);
  u64 a = ((u64)rhi[0] << 32) | rlo[0];
  u64 b = ((u64)rhi[1] << 32) | rlo[1];
  return umin64(k, umin64(a, b));
#else
  unsigned olo = (unsigned)__shfl_xor((int)lo, 32, 64);
  unsigned ohi = (unsigned)__shfl_xor((int)hi, 32, 64);
  return umin64(k, ((u64)ohi << 32) | olo);
#endif
}
static __device__ __forceinline__ u64 wave_min_u64(u64 k) {
  k = dpp_min64<0xB1>(k);
  k = dpp_min64<0x4E>(k);
  k = dpp_min64<0x141>(k);
  k = dpp_min64<0x140>(k);
  k = x16_min64(k);
  k = x32_min64(k);
  return k;  // wave-uniform
}

#define FOR16(M) M(0) M(1) M(2) M(3) M(4) M(5) M(6) M(7) \
                 M(8) M(9) M(10) M(11) M(12) M(13) M(14) M(15)

// Lane's 32 target columns in NAMED registers, as float2 pairs.
#define LOADP(h) \
  v2f TX##h, TY##h, TZ##h, TQ##h; \
  { float x0 = tb[6*h+0], y0 = tb[6*h+1], z0 = tb[6*h+2]; \
    float x1 = tb[6*h+3], y1 = tb[6*h+4], z1 = tb[6*h+5]; \
    TX##h = (v2f){x0, x1}; TY##h = (v2f){y0, y1}; TZ##h = (v2f){z0, z1}; \
    TQ##h = (v2f){x0*x0 + y0*y0 + z0*z0, x1*x1 + y1*y1 + z1*z1}; }

// ---------- phase 1: exact per-row sorted top-32, incremental tree ----------
#define DISTK(h) u64 KA##h, KB##h; { \
  v2f dot = __builtin_elementwise_fma(TX##h, Xv, \
              __builtin_elementwise_fma(TY##h, Yv, TZ##h * Zv)); \
  v2f dd  = __builtin_elementwise_fma(m2v, dot, TQ##h); \
  v2f d2  = Qv + dd; \
  float c0 = fmaxf(d2.x, 1e-12f), c1 = fmaxf(d2.y, 1e-12f); \
  KA##h = ((u64)(u32)__float_as_int(c0) << 32) | (u32)(base + 2*(h)); \
  KB##h = ((u64)(u32)__float_as_int(c1) << 32) | (u32)(base + 2*(h) + 1); }

#define G4(a, b, c, d) umin64(umin64(a, b), umin64(c, d))
#define ZG(c, KV, RL) case (c): KV = own ? ~0ULL : KV; goto RL;

__global__ __launch_bounds__(64, 2) void emd_topk_kernel(
    const float* __restrict__ pred, const float* __restrict__ target,
    u64* __restrict__ lists) {
  const int blk = blockIdx.x;
  const int b  = blk / (NPTS / RPB);
  const int r0 = (blk % (NPTS / RPB)) * RPB;
  const int lane = threadIdx.x;
  const float* p = pred + (size_t)b * NPTS * 3;
  const float* t = target + (size_t)b * NPTS * 3;

  const float* tb = t + (size_t)lane * 32 * 3;
  FOR16(LOADP)
  const int base = lane << 5;
  const v2f m2v = {-2.f, -2.f};

#pragma unroll 1
  for (int rr = 0; rr < RPB; ++rr) {
    const int i = r0 + rr;
    const float X = p[3 * i], Y = p[3 * i + 1], Z = p[3 * i + 2];
    const float Q = fmaf(X, X, fmaf(Y, Y, Z * Z));
    const v2f Xv = {X, X}, Yv = {Y, Y}, Zv = {Z, Z}, Qv = {Q, Q};
    FOR16(DISTK)

    u64 g0 = G4(KA0, KB0, KA1, KB1),   g1 = G4(KA2, KB2, KA3, KB3);
    u64 g2 = G4(KA4, KB4, KA5, KB5),   g3 = G4(KA6, KB6, KA7, KB7);
    u64 g4 = G4(KA8, KB8, KA9, KB9),   g5 = G4(KA10, KB10, KA11, KB11);
    u64 g6 = G4(KA12, KB12, KA13, KB13), g7 = G4(KA14, KB14, KA15, KB15);
    u64 h0 = umin64(g0, g1), h1 = umin64(g2, g3);
    u64 h2 = umin64(g4, g5), h3 = umin64(g6, g7);
    u64 q0 = umin64(h0, h1), q1 = umin64(h2, h3);
    u64 root = umin64(q0, q1);

    u64* out = lists + ((size_t)b * NPTS + i) * TOPK;
#pragma unroll 1
    for (int e = 0; e < TOPK; ++e) {
      u64 m = wave_min_u64(root);
      if (lane == 0) out[e] = m;
      if (e == TOPK - 1) break;
      const u32 col = (u32)m & (u32)(NPTS - 1);  // wave-uniform
      const bool own = (lane == (int)(col >> 5));
      const u32 k5 = col & 31u;
      switch (k5) {
        ZG(0,  KA0,  R0) ZG(1,  KB0,  R0) ZG(2,  KA1,  R0) ZG(3,  KB1,  R0)
        ZG(4,  KA2,  R1) ZG(5,  KB2,  R1) ZG(6,  KA3,  R1) ZG(7,  KB3,  R1)
        ZG(8,  KA4,  R2) ZG(9,  KB4,  R2) ZG(10, KA5,  R2) ZG(11, KB5,  R2)
        ZG(12, KA6,  R3) ZG(13, KB6,  R3) ZG(14, KA7,  R3) ZG(15, KB7,  R3)
        ZG(16, KA8,  R4) ZG(17, KB8,  R4) ZG(18, KA9,  R4) ZG(19, KB9,  R4)
        ZG(20, KA10, R5) ZG(21, KB10, R5) ZG(22, KA11, R5) ZG(23, KB11, R5)
        ZG(24, KA12, R6) ZG(25, KB12, R6) ZG(26, KA13, R6) ZG(27, KB13, R6)
        ZG(28, KA14, R7) ZG(29, KB14, R7) ZG(30, KA15, R7) ZG(31, KB15, R7)
        default: __builtin_unreachable();
      }
      R0: g0 = G4(KA0, KB0, KA1, KB1);     h0 = umin64(g0, g1); q0 = umin64(h0, h1); root = umin64(q0, q1); continue;
      R1: g1 = G4(KA2, KB2, KA3, KB3);     h0 = umin64(g0, g1); q0 = umin64(h0, h1); root = umin64(q0, q1); continue;
      R2: g2 = G4(KA4, KB4, KA5, KB5);     h1 = umin64(g2, g3); q0 = umin64(h0, h1); root = umin64(q0, q1); continue;
      R3: g3 = G4(KA6, KB6, KA7, KB7);     h1 = umin64(g2, g3); q0 = umin64(h0, h1); root = umin64(q0, q1); continue;
      R4: g4 = G4(KA8, KB8, KA9, KB9);     h2 = umin64(g4, g5); q1 = umin64(h2, h3); root = umin64(q0, q1); continue;
      R5: g5 = G4(KA10, KB10, KA11, KB11); h2 = umin64(g4, g5); q1 = umin64(h2, h3); root = umin64(q0, q1); continue;
      R6: g6 = G4(KA12, KB12, KA13, KB13); h3 = umin64(g6, g7); q1 = umin64(h2, h3); root = umin64(q0, q1); continue;
      R7: g7 = G4(KA14, KB14, KA15, KB15); h3 = umin64(g6, g7); q1 = umin64(h2, h3); root = umin64(q0, q1); continue;
    }
  }
}

// ---------- phase 2: block-parallel deferred acceptance ----------
// 64 rows resolved at once. Lane r = row (blk*64 + r). Used-set = LDS bitmap.
// Fixpoint: each row proposes its first candidate free vs the frozen bitmap;
// column conflicts resolved by atomicMin(claim[col], row); blocked rows
// advance. Fixpoint == serial greedy (earliest proposer of a column never
// leaves it). Any exhausted row -> exact serial scan for the whole block.

#define LD16(M) M(0) M(1) M(2) M(3) M(4) M(5) M(6) M(7) \
                M(8) M(9) M(10) M(11) M(12) M(13) M(14) M(15)
#define DECLA(j) uint4 A##j;
#define LDA(j)   A##j = Lr[j];
#define WRC(j)   wrow[j] = A##j;
#define FREEB(j) { \
    u32 c0 = A##j.x & 2047u, c1 = A##j.z & 2047u; \
    u32 w0 = sbm[c0 >> 5], w1 = sbm[c1 >> 5]; \
    alive |= ((~(w0 >> (c0 & 31u))) & 1u) << (2*(j)); \
    alive |= ((~(w1 >> (c1 & 31u))) & 1u) << (2*(j)+1); }

__global__ __launch_bounds__(64, 1) void emd_seq_kernel(
    const float* __restrict__ pred, const float* __restrict__ target,
    const u64* __restrict__ lists, float* __restrict__ batch_sums) {
  const int b = blockIdx.x, lane = threadIdx.x;
  const float* t = target + (size_t)b * NPTS * 3;

  __shared__ float4 tt[NPTS];       // fallback full-search table (32 KB)
  __shared__ uint4 cl4[64 * 17];    // block candidate lists, padded (17.4 KB)
  __shared__ u32 claim[NPTS];       // column claims (8 KB)
  __shared__ u32 sbitmap[64];       // used-columns bitmap (2048 bits)

  for (int j = lane; j < NPTS; j += 64) {
    float x = t[3 * j], y = t[3 * j + 1], z = t[3 * j + 2];
    tt[((j & 31) << 6) | ((j >> 5) ^ (j & 31))] =
        make_float4(x, y, z, fmaf(x, x, fmaf(y, y, z * z)));
  }
  sbitmap[lane] = 0u;
  __syncthreads();

  const u64* L = lists + (size_t)b * NPTS * TOPK;
  const u64* cl64 = (const u64*)cl4;
  volatile u32* sbm = sbitmap;
  volatile u32* vclaim = claim;
  float psum = 0.f;

  // prefetch block 0 candidate lists (lane r = row r)
  const uint4* Lr = (const uint4*)(L + (size_t)lane * TOPK);
  LD16(DECLA)
  LD16(LDA)

#pragma unroll 1
  for (int blk = 0; blk < NPTS / 64; ++blk) {
    // stage regs -> LDS
    uint4* wrow = &cl4[lane * 17];
    LD16(WRC)
    // availability vs frozen bitmap (cols still in regs)
    u32 alive = 0u;
    LD16(FREEB)
    // prefetch next block (latency hides under fixpoint)
    { int nrow = (blk + 1) * 64 + lane; nrow = nrow < NPTS ? nrow : NPTS - 1;
      Lr = (const uint4*)(L + (size_t)nrow * TOPK); }
    LD16(LDA)
    // reset claims
    { uint4 ff = make_uint4(~0u, ~0u, ~0u, ~0u);
      uint4* cr = (uint4*)&claim[lane * 32];
      cr[0] = ff; cr[1] = ff; cr[2] = ff; cr[3] = ff;
      cr[4] = ff; cr[5] = ff; cr[6] = ff; cr[7] = ff; }

    // ---- fixpoint ----
    bool exh = (alive == 0u);
    u32 rank = 0, col = 0;
    u64 cur = 0;
    if (!exh) {
      rank = (u32)__ffs(alive) - 1u;
      cur = cl64[lane * 34 + rank];
      col = (u32)cur & 2047u;
      atomicMin(&claim[col], (u32)lane);
    }
    bool bail = (__ballot(exh) != 0ULL);
    if (!bail) {
      int guard = 0;
      while (true) {
        bool changed = false;
        u32 c = vclaim[col];
        if (c < (u32)lane) {
          alive &= ~(1u << rank);
          if (alive == 0u) {
            exh = true;
          } else {
            rank = (u32)__ffs(alive) - 1u;
            cur = cl64[lane * 34 + rank];
            col = (u32)cur & 2047u;
            atomicMin(&claim[col], (u32)lane);
            changed = true;
          }
        }
        if (__ballot(exh) != 0ULL) { bail = true; break; }
        if (__ballot(changed) == 0ULL) break;
        if (++guard > 2048) { bail = true; break; }  // safety valve (exact path below)
      }
    }

    if (!bail) {
      // commit: 64 distinct winners
      atomicOr(&sbitmap[col >> 5], 1u << (col & 31u));
      psum += sqrtf(__uint_as_float((u32)(cur >> 32)));
    } else {
      // exact serial scan for the whole block (bitmap untouched by fixpoint)
      const int rbase = blk * 64;
#pragma unroll 1
      for (int r2 = 0; r2 < 64; ++r2) {
        u64 cand = cl64[r2 * 34 + (lane & 31)];
        u32 ccol = (u32)cand & 2047u;
        u32 wbit = (sbm[ccol >> 5] >> (ccol & 31u)) & 1u;
        u64 bl = __ballot(wbit == 0u && lane < 32);
        u32 wcol, whi;
        if (bl != 0ULL) {
          int R = __ffsll(bl) - 1;
          wcol = (u32)__builtin_amdgcn_readlane((int)ccol, R);
          whi  = (u32)__builtin_amdgcn_readlane((int)(u32)(cand >> 32), R);
        } else {
          // full masked search over all columns
          u32 um = sbm[lane];
          const float* pr = pred + ((size_t)b * NPTS + rbase + r2) * 3;
          float X = pr[0], Y = pr[1], Z = pr[2];
          float Q = fmaf(X, X, fmaf(Y, Y, Z * Z));
          u64 mb = ~0ULL;
          for (int k = 0; k < 32; ++k) {
            float4 c4 = tt[(k << 6) | (lane ^ k)];
            float dot = fmaf(c4.x, X, fmaf(c4.y, Y, c4.z * Z));
            float d2 = Q + fmaf(-2.f, dot, c4.w);
            d2 = fmaxf(d2, 1e-12f);
            u64 kk = ((u64)(u32)__float_as_int(d2) << 32) | (u32)((lane << 5) + k);
            if ((um >> k) & 1u) kk = ~0ULL;
            mb = umin64(mb, kk);
          }
          mb = wave_min_u64(mb);
          wcol = (u32)mb & 2047u;
          whi = (u32)(mb >> 32);
        }
        if (lane == (int)(wcol >> 5)) sbitmap[wcol >> 5] |= (1u << (wcol & 31u));
        if (lane == 0) psum += sqrtf(__uint_as_float(whi));
      }
    }
  }

  // final deterministic reduce of per-lane partials
  float v = psum;
  v += __shfl_xor(v, 1, 64);
  v += __shfl_xor(v, 2, 64);
  v += __shfl_xor(v, 4, 64);
  v += __shfl_xor(v, 8, 64);
  v += __shfl_xor(v, 16, 64);
  v += __shfl_xor(v, 32, 64);
  if (lane == 0) batch_sums[b] = v;
}

// ---------- legacy single-kernel path (round-5, proven; ws-too-small) ----------
#define DECLRU(h) v2u RU##h;
#define DIST(h) { \
  v2f dot = __builtin_elementwise_fma(TX##h, Xv, \
              __builtin_elementwise_fma(TY##h, Yv, TZ##h * Zv)); \
  v2f dd  = __builtin_elementwise_fma(m2v, dot, TQ##h); \
  v2f d2  = Qv + dd; \
  RU##h = (v2u){(u32)__float_as_int(d2.x), (u32)__float_as_int(d2.y)}; }
#define TOUR(h, c) { \
  u32 u0 = RU##h.x | sext_bit(usedmask, 2*h); \
  u32 u1 = RU##h.y | sext_bit(usedmask, 2*h + 1); \
  u32 pu = umin32(u0, u1); \
  u32 pk = (u1 < u0) ? (u32)(2*h + 1) : (u32)(2*h); \
  if (pu < bc##c) { bc##c = pu; kc##c = pk; } }

__global__ __launch_bounds__(64, 1) void emd_greedy_kernel(
    const float* __restrict__ pred, const float* __restrict__ target,
    float* __restrict__ batch_sums) {
  const int b = blockIdx.x, lane = threadIdx.x;
  const float* p = pred + (size_t)b * NPTS * 3;
  const float* t = target + (size_t)b * NPTS * 3;
  __shared__ float4 pp[NPTS + 2];
  for (int i = lane; i < NPTS; i += 64) {
    float x = p[3 * i], y = p[3 * i + 1], z = p[3 * i + 2];
    pp[i] = make_float4(x, y, z, x * x + y * y + z * z);
  }
  if (lane < 2) pp[NPTS + lane] = make_float4(0.f, 0.f, 0.f, 0.f);
  const float* tb = t + (size_t)lane * 32 * 3;
  FOR16(LOADP)
  FOR16(DECLRU)
  u32 usedmask = 0;
  float sum = 0.f;
  __syncthreads();
  const v2f m2v = {-2.f, -2.f};
  v2f Xv, Yv, Zv, Qv;
  {
    float4 A = pp[0];
    Xv = (v2f){A.x, A.x}; Yv = (v2f){A.y, A.y};
    Zv = (v2f){A.z, A.z}; Qv = (v2f){A.w, A.w};
    FOR16(DIST)
  }
  for (int i = 0; i < NPTS; ++i) {
    float4 An = pp[i + 1];
    u32 bc0 = ~0u, bc1 = ~0u, bc2 = ~0u, bc3 = ~0u;
    u32 kc0 = 0, kc1 = 0, kc2 = 0, kc3 = 0;
    TOUR(0, 0)  TOUR(1, 0)  TOUR(2, 0)  TOUR(3, 0)
    TOUR(4, 1)  TOUR(5, 1)  TOUR(6, 1)  TOUR(7, 1)
    TOUR(8, 2)  TOUR(9, 2)  TOUR(10, 2) TOUR(11, 2)
    TOUR(12, 3) TOUR(13, 3) TOUR(14, 3) TOUR(15, 3)
    bool s01 = bc1 < bc0; u32 v01 = s01 ? bc1 : bc0; u32 i01 = s01 ? kc1 : kc0;
    bool s23 = bc3 < bc2; u32 v23 = s23 ? bc3 : bc2; u32 i23 = s23 ? kc3 : kc2;
    bool sf  = v23 < v01; u32 bu  = sf ? v23 : v01; u32 bk  = sf ? i23 : i01;
    Xv = (v2f){An.x, An.x}; Yv = (v2f){An.y, An.y};
    Zv = (v2f){An.z, An.z}; Qv = (v2f){An.w, An.w};
    FOR16(DIST)
    u32 m = bu;
    m = dpp_min<0xB1>(m); m = dpp_min<0x4E>(m);
    m = dpp_min<0x141>(m); m = dpp_min<0x140>(m);
    m = x16_min(m); m = x32_min(m);
    u64 mk = __ballot(bu == m);
    int first = __ffsll(mk) - 1;
    usedmask |= (lane == first) ? (1u << bk) : 0u;
    sum += sqrtf(fmaxf(__uint_as_float(m), 1e-12f));
  }
  if (lane == 0) batch_sums[b] = sum;
}

// ---------- finalize ----------
__global__ void emd_finalize_kernel(const float* __restrict__ batch_sums,
                                    float* __restrict__ out, int B) {
  float acc = 0.f;
  for (int b = 0; b < B; ++b) acc += batch_sums[b] / (float)NPTS;
  out[0] = acc / (float)B;
}

extern "C" void kernel_launch(void* const* d_in, const int* in_sizes, int n_in,
                              void* d_out, int out_size, void* d_ws, size_t ws_size,
                              hipStream_t stream) {
  const float* pred   = (const float*)d_in[0];
  const float* target = (const float*)d_in[1];
  float* out = (float*)d_out;
  const int B = in_sizes[0] / (NPTS * 3);

  const size_t need = 256 + (size_t)B * NPTS * TOPK * sizeof(u64);
  if (ws_size >= need) {
    float* bs = (float*)d_ws;
    u64* lists = (u64*)((char*)d_ws + 256);
    emd_topk_kernel<<<B * (NPTS / RPB), 64, 0, stream>>>(pred, target, lists);
    emd_seq_kernel<<<B, 64, 0, stream>>>(pred, target, lists, bs);
    emd_finalize_kernel<<<1, 1, 0, stream>>>(bs, out, B);
  } else {
    float* bs = (float*)d_ws;
    emd_greedy_kernel<<<B, 64, 0, stream>>>(pred, target, bs);
    emd_finalize_kernel<<<1, 1, 0, stream>>>(bs, out, B);
  }
}

// Round 11
// 484.261 us; speedup vs baseline: 1.6484x; 1.5658x over previous
//
#include <hip/hip_runtime.h>

#define NPTS 2048
#define TOPK 32
#define RPB  8   // rows per block in phase 1

typedef float v2f __attribute__((ext_vector_type(2)));
typedef unsigned int u32;
typedef u32 v2u __attribute__((ext_vector_type(2)));
typedef unsigned long long u64;

// ---------- helpers ----------
static __device__ __forceinline__ u32 umin32(u32 a, u32 b) { return b < a ? b : a; }
static __device__ __forceinline__ u64 umin64(u64 a, u64 b) { return b < a ? b : a; }

template <int CTRL>
static __device__ __forceinline__ u32 dpp_min(u32 m) {
  return umin32(m, (u32)__builtin_amdgcn_mov_dpp((int)m, CTRL, 0xF, 0xF, true));
}
static __device__ __forceinline__ u32 x16_min(u32 m) {
#if __has_builtin(__builtin_amdgcn_permlane16_swap)
  auto r = __builtin_amdgcn_permlane16_swap((int)m, (int)m, false, false);
  return umin32(m, umin32((u32)r[0], (u32)r[1]));
#else
  return umin32(m, (u32)__builtin_amdgcn_ds_swizzle((int)m, 0x401F));
#endif
}
static __device__ __forceinline__ u32 x32_min(u32 m) {
#if __has_builtin(__builtin_amdgcn_permlane32_swap)
  auto r = __builtin_amdgcn_permlane32_swap((int)m, (int)m, false, false);
  return umin32(m, umin32((u32)r[0], (u32)r[1]));
#else
  return umin32(m, (u32)__shfl_xor((int)m, 32, 64));
#endif
}
static __device__ __forceinline__ u32 sext_bit(u32 mask, int c) {
#if __has_builtin(__builtin_amdgcn_sbfe)
  return (u32)__builtin_amdgcn_sbfe((int)mask, c, 1);
#else
  return (u32)(((int)(mask << (31 - c))) >> 31);
#endif
}

template <int CTRL>
static __device__ __forceinline__ u64 dpp_min64(u64 k) {
  unsigned lo = (unsigned)k, hi = (unsigned)(k >> 32);
  unsigned olo = (unsigned)__builtin_amdgcn_mov_dpp((int)lo, CTRL, 0xF, 0xF, true);
  unsigned ohi = (unsigned)__builtin_amdgcn_mov_dpp((int)hi, CTRL, 0xF, 0xF, true);
  return umin64(k, ((u64)ohi << 32) | olo);
}
static __device__ __forceinline__ u64 x16_min64(u64 k) {
  unsigned lo = (unsigned)k, hi = (unsigned)(k >> 32);
#if __has_builtin(__builtin_amdgcn_permlane16_swap)
  auto rlo = __builtin_amdgcn_permlane16_swap(lo, lo, false, false);
  auto rhi = __builtin_amdgcn_permlane16_swap(hi, hi, false, false);
  u64 a = ((u64)rhi[0] << 32) | rlo[0];
  u64 b = ((u64)rhi[1] << 32) | rlo[1];
  return umin64(k, umin64(a, b));
#else
  unsigned olo = (unsigned)__builtin_amdgcn_ds_swizzle((int)lo, 0x401F);
  unsigned ohi = (unsigned)__builtin_amdgcn_ds_swizzle((int)hi, 0x401F);
  return umin64(k, ((u64)ohi << 32) | olo);
#endif
}
static __device__ __forceinline__ u64 x32_min64(u64 k) {
  unsigned lo = (unsigned)k, hi = (unsigned)(k >> 32);
#if __has_builtin(__builtin_amdgcn_permlane32_swap)
  auto rlo = __builtin_amdgcn_permlane32_swap(lo, lo, false, false);
  auto rhi = __builtin_amdgcn_permlane32_swap(hi, hi, false, false);
  u64 a = ((u64)rhi[0] << 32) | rlo[0];
  u64 b = ((u64)rhi[1] << 32) | rlo[1];
  return umin64(k, umin64(a, b));
#else
  unsigned olo = (unsigned)__shfl_xor((int)lo, 32, 64);
  unsigned ohi = (unsigned)__shfl_xor((int)hi, 32, 64);
  return umin64(k, ((u64)ohi << 32) | olo);
#endif
}
static __device__ __forceinline__ u64 wave_min_u64(u64 k) {
  k = dpp_min64<0xB1>(k);
  k = dpp_min64<0x4E>(k);
  k = dpp_min64<0x141>(k);
  k = dpp_min64<0x140>(k);
  k = x16_min64(k);
  k = x32_min64(k);
  return k;  // wave-uniform
}

#define FOR16(M) M(0) M(1) M(2) M(3) M(4) M(5) M(6) M(7) \
                 M(8) M(9) M(10) M(11) M(12) M(13) M(14) M(15)

// Lane's 32 target columns in NAMED registers, as float2 pairs.
#define LOADP(h) \
  v2f TX##h, TY##h, TZ##h, TQ##h; \
  { float x0 = tb[6*h+0], y0 = tb[6*h+1], z0 = tb[6*h+2]; \
    float x1 = tb[6*h+3], y1 = tb[6*h+4], z1 = tb[6*h+5]; \
    TX##h = (v2f){x0, x1}; TY##h = (v2f){y0, y1}; TZ##h = (v2f){z0, z1}; \
    TQ##h = (v2f){x0*x0 + y0*y0 + z0*z0, x1*x1 + y1*y1 + z1*z1}; }

// ---------- phase 1: exact per-row sorted top-32, incremental tree ----------
#define DISTK(h) u64 KA##h, KB##h; { \
  v2f dot = __builtin_elementwise_fma(TX##h, Xv, \
              __builtin_elementwise_fma(TY##h, Yv, TZ##h * Zv)); \
  v2f dd  = __builtin_elementwise_fma(m2v, dot, TQ##h); \
  v2f d2  = Qv + dd; \
  float c0 = fmaxf(d2.x, 1e-12f), c1 = fmaxf(d2.y, 1e-12f); \
  KA##h = ((u64)(u32)__float_as_int(c0) << 32) | (u32)(base + 2*(h)); \
  KB##h = ((u64)(u32)__float_as_int(c1) << 32) | (u32)(base + 2*(h) + 1); }

#define G4(a, b, c, d) umin64(umin64(a, b), umin64(c, d))
#define ZG(c, KV, RL) case (c): KV = own ? ~0ULL : KV; goto RL;

__global__ __launch_bounds__(64, 2) void emd_topk_kernel(
    const float* __restrict__ pred, const float* __restrict__ target,
    u64* __restrict__ lists) {
  const int blk = blockIdx.x;
  const int b  = blk / (NPTS / RPB);
  const int r0 = (blk % (NPTS / RPB)) * RPB;
  const int lane = threadIdx.x;
  const float* p = pred + (size_t)b * NPTS * 3;
  const float* t = target + (size_t)b * NPTS * 3;

  const float* tb = t + (size_t)lane * 32 * 3;
  FOR16(LOADP)
  const int base = lane << 5;
  const v2f m2v = {-2.f, -2.f};

#pragma unroll 1
  for (int rr = 0; rr < RPB; ++rr) {
    const int i = r0 + rr;
    const float X = p[3 * i], Y = p[3 * i + 1], Z = p[3 * i + 2];
    const float Q = fmaf(X, X, fmaf(Y, Y, Z * Z));
    const v2f Xv = {X, X}, Yv = {Y, Y}, Zv = {Z, Z}, Qv = {Q, Q};
    FOR16(DISTK)

    u64 g0 = G4(KA0, KB0, KA1, KB1),   g1 = G4(KA2, KB2, KA3, KB3);
    u64 g2 = G4(KA4, KB4, KA5, KB5),   g3 = G4(KA6, KB6, KA7, KB7);
    u64 g4 = G4(KA8, KB8, KA9, KB9),   g5 = G4(KA10, KB10, KA11, KB11);
    u64 g6 = G4(KA12, KB12, KA13, KB13), g7 = G4(KA14, KB14, KA15, KB15);
    u64 h0 = umin64(g0, g1), h1 = umin64(g2, g3);
    u64 h2 = umin64(g4, g5), h3 = umin64(g6, g7);
    u64 q0 = umin64(h0, h1), q1 = umin64(h2, h3);
    u64 root = umin64(q0, q1);

    u64* out = lists + ((size_t)b * NPTS + i) * TOPK;
#pragma unroll 1
    for (int e = 0; e < TOPK; ++e) {
      u64 m = wave_min_u64(root);
      if (lane == 0) out[e] = m;
      if (e == TOPK - 1) break;
      const u32 col = (u32)m & (u32)(NPTS - 1);  // wave-uniform
      const bool own = (lane == (int)(col >> 5));
      const u32 k5 = col & 31u;
      switch (k5) {
        ZG(0,  KA0,  R0) ZG(1,  KB0,  R0) ZG(2,  KA1,  R0) ZG(3,  KB1,  R0)
        ZG(4,  KA2,  R1) ZG(5,  KB2,  R1) ZG(6,  KA3,  R1) ZG(7,  KB3,  R1)
        ZG(8,  KA4,  R2) ZG(9,  KB4,  R2) ZG(10, KA5,  R2) ZG(11, KB5,  R2)
        ZG(12, KA6,  R3) ZG(13, KB6,  R3) ZG(14, KA7,  R3) ZG(15, KB7,  R3)
        ZG(16, KA8,  R4) ZG(17, KB8,  R4) ZG(18, KA9,  R4) ZG(19, KB9,  R4)
        ZG(20, KA10, R5) ZG(21, KB10, R5) ZG(22, KA11, R5) ZG(23, KB11, R5)
        ZG(24, KA12, R6) ZG(25, KB12, R6) ZG(26, KA13, R6) ZG(27, KB13, R6)
        ZG(28, KA14, R7) ZG(29, KB14, R7) ZG(30, KA15, R7) ZG(31, KB15, R7)
        default: __builtin_unreachable();
      }
      R0: g0 = G4(KA0, KB0, KA1, KB1);     h0 = umin64(g0, g1); q0 = umin64(h0, h1); root = umin64(q0, q1); continue;
      R1: g1 = G4(KA2, KB2, KA3, KB3);     h0 = umin64(g0, g1); q0 = umin64(h0, h1); root = umin64(q0, q1); continue;
      R2: g2 = G4(KA4, KB4, KA5, KB5);     h1 = umin64(g2, g3); q0 = umin64(h0, h1); root = umin64(q0, q1); continue;
      R3: g3 = G4(KA6, KB6, KA7, KB7);     h1 = umin64(g2, g3); q0 = umin64(h0, h1); root = umin64(q0, q1); continue;
      R4: g4 = G4(KA8, KB8, KA9, KB9);     h2 = umin64(g4, g5); q1 = umin64(h2, h3); root = umin64(q0, q1); continue;
      R5: g5 = G4(KA10, KB10, KA11, KB11); h2 = umin64(g4, g5); q1 = umin64(h2, h3); root = umin64(q0, q1); continue;
      R6: g6 = G4(KA12, KB12, KA13, KB13); h3 = umin64(g6, g7); q1 = umin64(h2, h3); root = umin64(q0, q1); continue;
      R7: g7 = G4(KA14, KB14, KA15, KB15); h3 = umin64(g6, g7); q1 = umin64(h2, h3); root = umin64(q0, q1); continue;
    }
  }
}

// ---------- phase 2: block-parallel deferred acceptance, partial commit ----------
// 64 rows/block. Fixpoint == serial greedy for rows < r* (first exhausted
// row): claims by later rows never displace earlier ones. Commit rows < r*,
// serial-scan rows >= r* (rare); exhausted serial rows search only the
// compact FREE LIST (F = 2048 - #used entries), not all 2048 columns.

#define LD16(M) M(0) M(1) M(2) M(3) M(4) M(5) M(6) M(7) \
                M(8) M(9) M(10) M(11) M(12) M(13) M(14) M(15)
#define DECLA(j) uint4 A##j;
#define LDA(j)   A##j = Lr[j];
#define WRC(j)   wrow[j] = A##j;
#define FREEB(j) { \
    u32 c0 = A##j.x & 2047u, c1 = A##j.z & 2047u; \
    u32 w0 = sbm[c0 >> 5], w1 = sbm[c1 >> 5]; \
    alive |= ((~(w0 >> (c0 & 31u))) & 1u) << (2*(j)); \
    alive |= ((~(w1 >> (c1 & 31u))) & 1u) << (2*(j)+1); }

__global__ __launch_bounds__(64, 1) void emd_seq_kernel(
    const float* __restrict__ pred, const float* __restrict__ target,
    const u64* __restrict__ lists, float* __restrict__ batch_sums) {
  const int b = blockIdx.x, lane = threadIdx.x;
  const float* t = target + (size_t)b * NPTS * 3;

  __shared__ float4 tt[NPTS];       // target coords for free-list search (32 KB)
  __shared__ uint4 cl4[64 * 17];    // block candidate lists, padded (17.4 KB)
  __shared__ u32 claim[NPTS];       // column claims (8 KB)
  __shared__ u32 fl[NPTS];          // compact free list (8 KB)
  __shared__ u32 sbitmap[64];       // used-columns bitmap

  for (int j = lane; j < NPTS; j += 64) {
    float x = t[3 * j], y = t[3 * j + 1], z = t[3 * j + 2];
    tt[((j & 31) << 6) | ((j >> 5) ^ (j & 31))] =
        make_float4(x, y, z, fmaf(x, x, fmaf(y, y, z * z)));
  }
  sbitmap[lane] = 0u;
  __syncthreads();

  const u64* L = lists + (size_t)b * NPTS * TOPK;
  const u64* cl64 = (const u64*)cl4;
  volatile u32* sbm = sbitmap;
  volatile u32* vclaim = claim;
  float psum = 0.f;

  const uint4* Lr = (const uint4*)(L + (size_t)lane * TOPK);
  LD16(DECLA)
  LD16(LDA)

#pragma unroll 1
  for (int blk = 0; blk < NPTS / 64; ++blk) {
    uint4* wrow = &cl4[lane * 17];
    LD16(WRC)
    u32 alive = 0u;
    LD16(FREEB)
    { int nrow = (blk + 1) * 64 + lane; nrow = nrow < NPTS ? nrow : NPTS - 1;
      Lr = (const uint4*)(L + (size_t)nrow * TOPK); }
    LD16(LDA)
    // conflict-free claim reset (stride-64 per lane)
#pragma unroll
    for (int k = 0; k < 32; ++k) claim[k * 64 + lane] = ~0u;

    // ---- fixpoint (exhausted lanes drop out, others continue) ----
    bool exh = (alive == 0u);
    u32 rank = 0, col = 0;
    u64 cur = 0;
    if (!exh) {
      rank = (u32)__ffs(alive) - 1u;
      cur = cl64[lane * 34 + rank];
      col = (u32)cur & 2047u;
      atomicMin(&claim[col], (u32)lane);
    }
    bool forced = false;
    int guard = 0;
    while (true) {
      bool changed = false;
      if (!exh) {
        u32 c = vclaim[col];
        if (c < (u32)lane) {
          alive &= ~(1u << rank);
          if (alive == 0u) {
            exh = true;
          } else {
            rank = (u32)__ffs(alive) - 1u;
            cur = cl64[lane * 34 + rank];
            col = (u32)cur & 2047u;
            atomicMin(&claim[col], (u32)lane);
            changed = true;
          }
        }
      }
      if (__ballot(changed) == 0ULL) break;
      if (++guard > 4096) { forced = true; break; }
    }

    u64 exbl = __ballot(exh);
    int rstar = forced ? 0 : (exbl ? (__ffsll(exbl) - 1) : 64);

    // commit exact fixpoint winners for rows < r*
    if (lane < rstar) {
      atomicOr(&sbitmap[col >> 5], 1u << (col & 31u));
      psum += sqrtf(__uint_as_float((u32)(cur >> 32)));
    }

    if (rstar < 64) {
      // build compact free list from the live bitmap
      u32 word = sbm[lane];
      u32 fw = ~word;
      u32 cnt = __popc(fw);
      u32 pfx = cnt;
#pragma unroll
      for (int d = 1; d < 64; d <<= 1) {
        u32 o = (u32)__shfl_up((int)pfx, d, 64);
        if (lane >= d) pfx += o;
      }
      u32 F = (u32)__shfl((int)pfx, 63, 64);
      pfx -= cnt;  // exclusive
      while (fw) {
        int bpos = __ffs(fw) - 1;
        fw &= fw - 1u;
        fl[pfx++] = ((u32)lane << 5) + (u32)bpos;
      }

      // serial scan for rows r*..63
      const int rbase = blk * 64;
#pragma unroll 1
      for (int r2 = rstar; r2 < 64; ++r2) {
        u64 cand = cl64[r2 * 34 + (lane & 31)];
        u32 ccol = (u32)cand & 2047u;
        u32 ubit = (sbm[ccol >> 5] >> (ccol & 31u)) & 1u;
        u64 bl = __ballot(ubit == 0u && lane < 32);
        u32 wcol, whi;
        if (bl != 0ULL) {
          int R = __ffsll(bl) - 1;
          wcol = (u32)__builtin_amdgcn_readlane((int)ccol, R);
          whi  = (u32)__builtin_amdgcn_readlane((int)(u32)(cand >> 32), R);
        } else {
          // exhausted: search only the free list
          const float* pr = pred + ((size_t)b * NPTS + rbase + r2) * 3;
          float X = pr[0], Y = pr[1], Z = pr[2];
          float Q = fmaf(X, X, fmaf(Y, Y, Z * Z));
          u64 mb = ~0ULL;
          for (u32 k = (u32)lane; k < F; k += 64) {
            u32 c = fl[k];
            u32 ub2 = (sbm[c >> 5] >> (c & 31u)) & 1u;  // consumed this scan?
            float4 c4 = tt[((c & 31u) << 6) | ((c >> 5) ^ (c & 31u))];
            float dot = fmaf(c4.x, X, fmaf(c4.y, Y, c4.z * Z));
            float d2 = Q + fmaf(-2.f, dot, c4.w);
            d2 = fmaxf(d2, 1e-12f);
            u64 kk = ((u64)(u32)__float_as_int(d2) << 32) | c;
            if (ub2) kk = ~0ULL;
            mb = umin64(mb, kk);
          }
          mb = wave_min_u64(mb);
          wcol = (u32)mb & 2047u;
          whi = (u32)(mb >> 32);
        }
        if (lane == 0) {
          atomicOr(&sbitmap[wcol >> 5], 1u << (wcol & 31u));
          psum += sqrtf(__uint_as_float(whi));
        }
      }
    }
  }

  float v = psum;
  v += __shfl_xor(v, 1, 64);
  v += __shfl_xor(v, 2, 64);
  v += __shfl_xor(v, 4, 64);
  v += __shfl_xor(v, 8, 64);
  v += __shfl_xor(v, 16, 64);
  v += __shfl_xor(v, 32, 64);
  if (lane == 0) batch_sums[b] = v;
}

// ---------- legacy single-kernel path (round-5, proven; ws-too-small) ----------
#define DECLRU(h) v2u RU##h;
#define DIST(h) { \
  v2f dot = __builtin_elementwise_fma(TX##h, Xv, \
              __builtin_elementwise_fma(TY##h, Yv, TZ##h * Zv)); \
  v2f dd  = __builtin_elementwise_fma(m2v, dot, TQ##h); \
  v2f d2  = Qv + dd; \
  RU##h = (v2u){(u32)__float_as_int(d2.x), (u32)__float_as_int(d2.y)}; }
#define TOUR(h, c) { \
  u32 u0 = RU##h.x | sext_bit(usedmask, 2*h); \
  u32 u1 = RU##h.y | sext_bit(usedmask, 2*h + 1); \
  u32 pu = umin32(u0, u1); \
  u32 pk = (u1 < u0) ? (u32)(2*h + 1) : (u32)(2*h); \
  if (pu < bc##c) { bc##c = pu; kc##c = pk; } }

__global__ __launch_bounds__(64, 1) void emd_greedy_kernel(
    const float* __restrict__ pred, const float* __restrict__ target,
    float* __restrict__ batch_sums) {
  const int b = blockIdx.x, lane = threadIdx.x;
  const float* p = pred + (size_t)b * NPTS * 3;
  const float* t = target + (size_t)b * NPTS * 3;
  __shared__ float4 pp[NPTS + 2];
  for (int i = lane; i < NPTS; i += 64) {
    float x = p[3 * i], y = p[3 * i + 1], z = p[3 * i + 2];
    pp[i] = make_float4(x, y, z, x * x + y * y + z * z);
  }
  if (lane < 2) pp[NPTS + lane] = make_float4(0.f, 0.f, 0.f, 0.f);
  const float* tb = t + (size_t)lane * 32 * 3;
  FOR16(LOADP)
  FOR16(DECLRU)
  u32 usedmask = 0;
  float sum = 0.f;
  __syncthreads();
  const v2f m2v = {-2.f, -2.f};
  v2f Xv, Yv, Zv, Qv;
  {
    float4 A = pp[0];
    Xv = (v2f){A.x, A.x}; Yv = (v2f){A.y, A.y};
    Zv = (v2f){A.z, A.z}; Qv = (v2f){A.w, A.w};
    FOR16(DIST)
  }
  for (int i = 0; i < NPTS; ++i) {
    float4 An = pp[i + 1];
    u32 bc0 = ~0u, bc1 = ~0u, bc2 = ~0u, bc3 = ~0u;
    u32 kc0 = 0, kc1 = 0, kc2 = 0, kc3 = 0;
    TOUR(0, 0)  TOUR(1, 0)  TOUR(2, 0)  TOUR(3, 0)
    TOUR(4, 1)  TOUR(5, 1)  TOUR(6, 1)  TOUR(7, 1)
    TOUR(8, 2)  TOUR(9, 2)  TOUR(10, 2) TOUR(11, 2)
    TOUR(12, 3) TOUR(13, 3) TOUR(14, 3) TOUR(15, 3)
    bool s01 = bc1 < bc0; u32 v01 = s01 ? bc1 : bc0; u32 i01 = s01 ? kc1 : kc0;
    bool s23 = bc3 < bc2; u32 v23 = s23 ? bc3 : bc2; u32 i23 = s23 ? kc3 : kc2;
    bool sf  = v23 < v01; u32 bu  = sf ? v23 : v01; u32 bk  = sf ? i23 : i01;
    Xv = (v2f){An.x, An.x}; Yv = (v2f){An.y, An.y};
    Zv = (v2f){An.z, An.z}; Qv = (v2f){An.w, An.w};
    FOR16(DIST)
    u32 m = bu;
    m = dpp_min<0xB1>(m); m = dpp_min<0x4E>(m);
    m = dpp_min<0x141>(m); m = dpp_min<0x140>(m);
    m = x16_min(m); m = x32_min(m);
    u64 mk = __ballot(bu == m);
    int first = __ffsll(mk) - 1;
    usedmask |= (lane == first) ? (1u << bk) : 0u;
    sum += sqrtf(fmaxf(__uint_as_float(m), 1e-12f));
  }
  if (lane == 0) batch_sums[b] = sum;
}

// ---------- finalize ----------
__global__ void emd_finalize_kernel(const float* __restrict__ batch_sums,
                                    float* __restrict__ out, int B) {
  float acc = 0.f;
  for (int b = 0; b < B; ++b) acc += batch_sums[b] / (float)NPTS;
  out[0] = acc / (float)B;
}

extern "C" void kernel_launch(void* const* d_in, const int* in_sizes, int n_in,
                              void* d_out, int out_size, void* d_ws, size_t ws_size,
                              hipStream_t stream) {
  const float* pred   = (const float*)d_in[0];
  const float* target = (const float*)d_in[1];
  float* out = (float*)d_out;
  const int B = in_sizes[0] / (NPTS * 3);

  const size_t need = 256 + (size_t)B * NPTS * TOPK * sizeof(u64);
  if (ws_size >= need) {
    float* bs = (float*)d_ws;
    u64* lists = (u64*)((char*)d_ws + 256);
    emd_topk_kernel<<<B * (NPTS / RPB), 64, 0, stream>>>(pred, target, lists);
    emd_seq_kernel<<<B, 64, 0, stream>>>(pred, target, lists, bs);
    emd_finalize_kernel<<<1, 1, 0, stream>>>(bs, out, B);
  } else {
    float* bs = (float*)d_ws;
    emd_greedy_kernel<<<B, 64, 0, stream>>>(pred, target, bs);
    emd_finalize_kernel<<<1, 1, 0, stream>>>(bs, out, B);
  }
}

// Round 12
// 461.011 us; speedup vs baseline: 1.7316x; 1.0504x over previous
//
#include <hip/hip_runtime.h>

#define NPTS 2048
#define TOPK 32
#define RPB  8   // rows per block in phase 1

typedef float v2f __attribute__((ext_vector_type(2)));
typedef unsigned int u32;
typedef u32 v2u __attribute__((ext_vector_type(2)));
typedef unsigned long long u64;

// ---------- helpers ----------
static __device__ __forceinline__ u32 umin32(u32 a, u32 b) { return b < a ? b : a; }
static __device__ __forceinline__ u64 umin64(u64 a, u64 b) { return b < a ? b : a; }

template <int CTRL>
static __device__ __forceinline__ u32 dpp_min(u32 m) {
  return umin32(m, (u32)__builtin_amdgcn_mov_dpp((int)m, CTRL, 0xF, 0xF, true));
}
static __device__ __forceinline__ u32 x16_min(u32 m) {
#if __has_builtin(__builtin_amdgcn_permlane16_swap)
  auto r = __builtin_amdgcn_permlane16_swap((int)m, (int)m, false, false);
  return umin32(m, umin32((u32)r[0], (u32)r[1]));
#else
  return umin32(m, (u32)__builtin_amdgcn_ds_swizzle((int)m, 0x401F));
#endif
}
static __device__ __forceinline__ u32 x32_min(u32 m) {
#if __has_builtin(__builtin_amdgcn_permlane32_swap)
  auto r = __builtin_amdgcn_permlane32_swap((int)m, (int)m, false, false);
  return umin32(m, umin32((u32)r[0], (u32)r[1]));
#else
  return umin32(m, (u32)__shfl_xor((int)m, 32, 64));
#endif
}
static __device__ __forceinline__ u32 sext_bit(u32 mask, int c) {
#if __has_builtin(__builtin_amdgcn_sbfe)
  return (u32)__builtin_amdgcn_sbfe((int)mask, c, 1);
#else
  return (u32)(((int)(mask << (31 - c))) >> 31);
#endif
}

template <int CTRL>
static __device__ __forceinline__ u64 dpp_min64(u64 k) {
  unsigned lo = (unsigned)k, hi = (unsigned)(k >> 32);
  unsigned olo = (unsigned)__builtin_amdgcn_mov_dpp((int)lo, CTRL, 0xF, 0xF, true);
  unsigned ohi = (unsigned)__builtin_amdgcn_mov_dpp((int)hi, CTRL, 0xF, 0xF, true);
  return umin64(k, ((u64)ohi << 32) | olo);
}
static __device__ __forceinline__ u64 x16_min64(u64 k) {
  unsigned lo = (unsigned)k, hi = (unsigned)(k >> 32);
#if __has_builtin(__builtin_amdgcn_permlane16_swap)
  auto rlo = __builtin_amdgcn_permlane16_swap(lo, lo, false, false);
  auto rhi = __builtin_amdgcn_permlane16_swap(hi, hi, false, false);
  u64 a = ((u64)rhi[0] << 32) | rlo[0];
  u64 b = ((u64)rhi[1] << 32) | rlo[1];
  return umin64(k, umin64(a, b));
#else
  unsigned olo = (unsigned)__builtin_amdgcn_ds_swizzle((int)lo, 0x401F);
  unsigned ohi = (unsigned)__builtin_amdgcn_ds_swizzle((int)hi, 0x401F);
  return umin64(k, ((u64)ohi << 32) | olo);
#endif
}
static __device__ __forceinline__ u64 x32_min64(u64 k) {
  unsigned lo = (unsigned)k, hi = (unsigned)(k >> 32);
#if __has_builtin(__builtin_amdgcn_permlane32_swap)
  auto rlo = __builtin_amdgcn_permlane32_swap(lo, lo, false, false);
  auto rhi = __builtin_amdgcn_permlane32_swap(hi, hi, false, false);
  u64 a = ((u64)rhi[0] << 32) | rlo[0];
  u64 b = ((u64)rhi[1] << 32) | rlo[1];
  return umin64(k, umin64(a, b));
#else
  unsigned olo = (unsigned)__shfl_xor((int)lo, 32, 64);
  unsigned ohi = (unsigned)__shfl_xor((int)hi, 32, 64);
  return umin64(k, ((u64)ohi << 32) | olo);
#endif
}
static __device__ __forceinline__ u64 wave_min_u64(u64 k) {
  k = dpp_min64<0xB1>(k);
  k = dpp_min64<0x4E>(k);
  k = dpp_min64<0x141>(k);
  k = dpp_min64<0x140>(k);
  k = x16_min64(k);
  k = x32_min64(k);
  return k;  // wave-uniform
}

#define FOR16(M) M(0) M(1) M(2) M(3) M(4) M(5) M(6) M(7) \
                 M(8) M(9) M(10) M(11) M(12) M(13) M(14) M(15)

// Lane's 32 target columns in NAMED registers, as float2 pairs.
#define LOADP(h) \
  v2f TX##h, TY##h, TZ##h, TQ##h; \
  { float x0 = tb[6*h+0], y0 = tb[6*h+1], z0 = tb[6*h+2]; \
    float x1 = tb[6*h+3], y1 = tb[6*h+4], z1 = tb[6*h+5]; \
    TX##h = (v2f){x0, x1}; TY##h = (v2f){y0, y1}; TZ##h = (v2f){z0, z1}; \
    TQ##h = (v2f){x0*x0 + y0*y0 + z0*z0, x1*x1 + y1*y1 + z1*z1}; }

// ---------- phase 1: exact per-row sorted top-32, incremental tree ----------
#define DISTK(h) u64 KA##h, KB##h; { \
  v2f dot = __builtin_elementwise_fma(TX##h, Xv, \
              __builtin_elementwise_fma(TY##h, Yv, TZ##h * Zv)); \
  v2f dd  = __builtin_elementwise_fma(m2v, dot, TQ##h); \
  v2f d2  = Qv + dd; \
  float c0 = fmaxf(d2.x, 1e-12f), c1 = fmaxf(d2.y, 1e-12f); \
  KA##h = ((u64)(u32)__float_as_int(c0) << 32) | (u32)(base + 2*(h)); \
  KB##h = ((u64)(u32)__float_as_int(c1) << 32) | (u32)(base + 2*(h) + 1); }

#define G4(a, b, c, d) umin64(umin64(a, b), umin64(c, d))
#define ZG(c, KV, RL) case (c): KV = own ? ~0ULL : KV; goto RL;

__global__ __launch_bounds__(64, 2) void emd_topk_kernel(
    const float* __restrict__ pred, const float* __restrict__ target,
    u64* __restrict__ lists) {
  const int blk = blockIdx.x;
  const int b  = blk / (NPTS / RPB);
  const int r0 = (blk % (NPTS / RPB)) * RPB;
  const int lane = threadIdx.x;
  const float* p = pred + (size_t)b * NPTS * 3;
  const float* t = target + (size_t)b * NPTS * 3;

  const float* tb = t + (size_t)lane * 32 * 3;
  FOR16(LOADP)
  const int base = lane << 5;
  const v2f m2v = {-2.f, -2.f};

#pragma unroll 1
  for (int rr = 0; rr < RPB; ++rr) {
    const int i = r0 + rr;
    const float X = p[3 * i], Y = p[3 * i + 1], Z = p[3 * i + 2];
    const float Q = fmaf(X, X, fmaf(Y, Y, Z * Z));
    const v2f Xv = {X, X}, Yv = {Y, Y}, Zv = {Z, Z}, Qv = {Q, Q};
    FOR16(DISTK)

    u64 g0 = G4(KA0, KB0, KA1, KB1),   g1 = G4(KA2, KB2, KA3, KB3);
    u64 g2 = G4(KA4, KB4, KA5, KB5),   g3 = G4(KA6, KB6, KA7, KB7);
    u64 g4 = G4(KA8, KB8, KA9, KB9),   g5 = G4(KA10, KB10, KA11, KB11);
    u64 g6 = G4(KA12, KB12, KA13, KB13), g7 = G4(KA14, KB14, KA15, KB15);
    u64 h0 = umin64(g0, g1), h1 = umin64(g2, g3);
    u64 h2 = umin64(g4, g5), h3 = umin64(g6, g7);
    u64 q0 = umin64(h0, h1), q1 = umin64(h2, h3);
    u64 root = umin64(q0, q1);

    u64* out = lists + ((size_t)b * NPTS + i) * TOPK;
#pragma unroll 1
    for (int e = 0; e < TOPK; ++e) {
      u64 m = wave_min_u64(root);
      if (lane == 0) out[e] = m;
      if (e == TOPK - 1) break;
      const u32 col = (u32)m & (u32)(NPTS - 1);  // wave-uniform
      const bool own = (lane == (int)(col >> 5));
      const u32 k5 = col & 31u;
      switch (k5) {
        ZG(0,  KA0,  R0) ZG(1,  KB0,  R0) ZG(2,  KA1,  R0) ZG(3,  KB1,  R0)
        ZG(4,  KA2,  R1) ZG(5,  KB2,  R1) ZG(6,  KA3,  R1) ZG(7,  KB3,  R1)
        ZG(8,  KA4,  R2) ZG(9,  KB4,  R2) ZG(10, KA5,  R2) ZG(11, KB5,  R2)
        ZG(12, KA6,  R3) ZG(13, KB6,  R3) ZG(14, KA7,  R3) ZG(15, KB7,  R3)
        ZG(16, KA8,  R4) ZG(17, KB8,  R4) ZG(18, KA9,  R4) ZG(19, KB9,  R4)
        ZG(20, KA10, R5) ZG(21, KB10, R5) ZG(22, KA11, R5) ZG(23, KB11, R5)
        ZG(24, KA12, R6) ZG(25, KB12, R6) ZG(26, KA13, R6) ZG(27, KB13, R6)
        ZG(28, KA14, R7) ZG(29, KB14, R7) ZG(30, KA15, R7) ZG(31, KB15, R7)
        default: __builtin_unreachable();
      }
      R0: g0 = G4(KA0, KB0, KA1, KB1);     h0 = umin64(g0, g1); q0 = umin64(h0, h1); root = umin64(q0, q1); continue;
      R1: g1 = G4(KA2, KB2, KA3, KB3);     h0 = umin64(g0, g1); q0 = umin64(h0, h1); root = umin64(q0, q1); continue;
      R2: g2 = G4(KA4, KB4, KA5, KB5);     h1 = umin64(g2, g3); q0 = umin64(h0, h1); root = umin64(q0, q1); continue;
      R3: g3 = G4(KA6, KB6, KA7, KB7);     h1 = umin64(g2, g3); q0 = umin64(h0, h1); root = umin64(q0, q1); continue;
      R4: g4 = G4(KA8, KB8, KA9, KB9);     h2 = umin64(g4, g5); q1 = umin64(h2, h3); root = umin64(q0, q1); continue;
      R5: g5 = G4(KA10, KB10, KA11, KB11); h2 = umin64(g4, g5); q1 = umin64(h2, h3); root = umin64(q0, q1); continue;
      R6: g6 = G4(KA12, KB12, KA13, KB13); h3 = umin64(g6, g7); q1 = umin64(h2, h3); root = umin64(q0, q1); continue;
      R7: g7 = G4(KA14, KB14, KA15, KB15); h3 = umin64(g6, g7); q1 = umin64(h2, h3); root = umin64(q0, q1); continue;
    }
  }
}

// ---------- phase 2: iterative prefix-commit deferred acceptance ----------
// 64 rows/block. Cascade to fixpoint; commit rows below the first exhausted
// row; resolve ONLY that row (free-list search vs live bitmap = exact since
// all earlier rows committed); inject its claim; re-cascade. Non-exhausted
// rows never serialize. Claims only decrease => row advances past col c iff
// final claim[c] < row (exactness induction as rounds 10-11, absmax 0).

#define LD16(M) M(0) M(1) M(2) M(3) M(4) M(5) M(6) M(7) \
                M(8) M(9) M(10) M(11) M(12) M(13) M(14) M(15)
#define DECLA(j) uint4 A##j;
#define LDA(j)   A##j = Lr[j];
// rank-major store: entry (rank k, row lane) at cl64[k*64+lane] (2-way, free)
#define WRC(j)   { cl64w[(2*(j)) * 64 + lane]     = ((u64)A##j.y << 32) | A##j.x; \
                   cl64w[(2*(j) + 1) * 64 + lane] = ((u64)A##j.w << 32) | A##j.z; }
#define FREEB(j) { \
    u32 c0 = A##j.x & 2047u, c1 = A##j.z & 2047u; \
    u32 w0 = sbm[c0 >> 5], w1 = sbm[c1 >> 5]; \
    alive |= ((~(w0 >> (c0 & 31u))) & 1u) << (2*(j)); \
    alive |= ((~(w1 >> (c1 & 31u))) & 1u) << (2*(j)+1); }

__global__ __launch_bounds__(64, 1) void emd_seq_kernel(
    const float* __restrict__ pred, const float* __restrict__ target,
    const u64* __restrict__ lists, float* __restrict__ batch_sums) {
  const int b = blockIdx.x, lane = threadIdx.x;
  const float* t = target + (size_t)b * NPTS * 3;
  const float* p = pred + (size_t)b * NPTS * 3;

  __shared__ float4 tt[NPTS];      // target coords for free search (32 KB)
  __shared__ u64 cl64s[TOPK * 64]; // block candidates, rank-major (16 KB)
  __shared__ u32 claim[NPTS];      // column claims (8 KB)
  __shared__ u32 fl[NPTS];         // compact free list (8 KB)
  __shared__ u32 sbitmap[64];      // used-columns bitmap
  __shared__ float4 ppred[64];     // this block's pred rows

  for (int j = lane; j < NPTS; j += 64) {
    float x = t[3 * j], y = t[3 * j + 1], z = t[3 * j + 2];
    tt[((j & 31) << 6) | ((j >> 5) ^ (j & 31))] =
        make_float4(x, y, z, fmaf(x, x, fmaf(y, y, z * z)));
  }
  sbitmap[lane] = 0u;
  __syncthreads();

  const u64* L = lists + (size_t)b * NPTS * TOPK;
  u64* cl64w = cl64s;
  const u64* cl64 = cl64s;
  volatile u32* sbm = sbitmap;
  volatile u32* vclaim = claim;
  float psum = 0.f;

  const uint4* Lr = (const uint4*)(L + (size_t)lane * TOPK);
  LD16(DECLA)
  LD16(LDA)

#pragma unroll 1
  for (int blk = 0; blk < NPTS / 64; ++blk) {
    LD16(WRC)
    u32 alive = 0u;
    LD16(FREEB)
    // stage this block's pred rows
    { const float* pr = p + (size_t)(blk * 64 + lane) * 3;
      float X = pr[0], Y = pr[1], Z = pr[2];
      ppred[lane] = make_float4(X, Y, Z, fmaf(X, X, fmaf(Y, Y, Z * Z))); }
    // prefetch next block's candidates
    { int nrow = (blk + 1) * 64 + lane; nrow = nrow < NPTS ? nrow : NPTS - 1;
      Lr = (const uint4*)(L + (size_t)nrow * TOPK); }
    LD16(LDA)
    // conflict-free claim reset
#pragma unroll
    for (int k = 0; k < 32; ++k) claim[k * 64 + lane] = ~0u;

    bool committed = false;
    bool exh = (alive == 0u);
    u32 rank = 0, col = 0;
    u64 cur = 0;
    if (!exh) {
      rank = (u32)__ffs(alive) - 1u;
      cur = cl64[rank * 64 + lane];
      col = (u32)cur & 2047u;
      atomicMin(&claim[col], (u32)lane);
    }
    bool flBuilt = false;
    u32 F = 0;

    int oguard = 0;
#pragma unroll 1
    while (true) {
      // ---- cascade to fixpoint (lanes chase locally, ballot globally) ----
      int guard = 0;
      while (true) {
        bool changed = false;
        if (!committed && !exh) {
          int g2 = 0;
          while (true) {
            u32 c = vclaim[col];
            if (c >= (u32)lane) break;  // we hold it (c == lane)
            alive &= ~(1u << rank);
            if (alive == 0u) { exh = true; break; }
            rank = (u32)__ffs(alive) - 1u;
            cur = cl64[rank * 64 + lane];
            col = (u32)cur & 2047u;
            atomicMin(&claim[col], (u32)lane);
            changed = true;
            if (++g2 > 33) break;
          }
        }
        if (__ballot(changed) == 0ULL) break;
        if (++guard > 3000) break;
      }

      u64 exbl = __ballot(exh && !committed);
      if (exbl == 0ULL) break;
      int rstar = __ffsll(exbl) - 1;

      // commit stable rows below rstar
      if (!committed && !exh && lane < rstar) {
        atomicOr(&sbitmap[col >> 5], 1u << (col & 31u));
        psum += sqrtf(__uint_as_float((u32)(cur >> 32)));
        committed = true;
      }

      // build free list once per block (entries only get consumed later)
      if (!flBuilt) {
        u32 fw = ~sbm[lane];
        u32 cnt = __popc(fw);
        u32 pfx = cnt;
#pragma unroll
        for (int d = 1; d < 64; d <<= 1) {
          u32 o = (u32)__shfl_up((int)pfx, d, 64);
          if (lane >= d) pfx += o;
        }
        F = (u32)__shfl((int)pfx, 63, 64);
        pfx -= cnt;
        while (fw) {
          int bpos = __ffs(fw) - 1;
          fw &= fw - 1u;
          fl[pfx++] = ((u32)lane << 5) + (u32)bpos;
        }
        flBuilt = true;
      }

      // exact resolve of row rstar: min over live free columns
      {
        float4 P4 = ppred[rstar];
        float X = P4.x, Y = P4.y, Z = P4.z, Q = P4.w;
        u64 mb = ~0ULL;
        for (u32 k = (u32)lane; k < F; k += 64) {
          u32 c = fl[k];
          u32 used = (sbm[c >> 5] >> (c & 31u)) & 1u;
          float4 c4 = tt[((c & 31u) << 6) | ((c >> 5) ^ (c & 31u))];
          float dot = fmaf(c4.x, X, fmaf(c4.y, Y, c4.z * Z));
          float d2 = Q + fmaf(-2.f, dot, c4.w);
          d2 = fmaxf(d2, 1e-12f);
          u64 kk = ((u64)(u32)__float_as_int(d2) << 32) | c;
          if (used) kk = ~0ULL;
          mb = umin64(mb, kk);
        }
        mb = wave_min_u64(mb);
        u32 cst = (u32)mb & 2047u;
        if (lane == rstar) {
          psum += sqrtf(__uint_as_float((u32)(mb >> 32)));
          committed = true;
          atomicOr(&sbitmap[cst >> 5], 1u << (cst & 31u));
          atomicMin(&claim[cst], (u32)rstar);
        }
      }
      if (++oguard > 66) break;
    }

    // commit all remaining stable rows
    if (!committed) {
      atomicOr(&sbitmap[col >> 5], 1u << (col & 31u));
      psum += sqrtf(__uint_as_float((u32)(cur >> 32)));
    }
  }

  float v = psum;
  v += __shfl_xor(v, 1, 64);
  v += __shfl_xor(v, 2, 64);
  v += __shfl_xor(v, 4, 64);
  v += __shfl_xor(v, 8, 64);
  v += __shfl_xor(v, 16, 64);
  v += __shfl_xor(v, 32, 64);
  if (lane == 0) batch_sums[b] = v;
}

// ---------- legacy single-kernel path (round-5, proven; ws-too-small) ----------
#define DECLRU(h) v2u RU##h;
#define DIST(h) { \
  v2f dot = __builtin_elementwise_fma(TX##h, Xv, \
              __builtin_elementwise_fma(TY##h, Yv, TZ##h * Zv)); \
  v2f dd  = __builtin_elementwise_fma(m2v, dot, TQ##h); \
  v2f d2  = Qv + dd; \
  RU##h = (v2u){(u32)__float_as_int(d2.x), (u32)__float_as_int(d2.y)}; }
#define TOUR(h, c) { \
  u32 u0 = RU##h.x | sext_bit(usedmask, 2*h); \
  u32 u1 = RU##h.y | sext_bit(usedmask, 2*h + 1); \
  u32 pu = umin32(u0, u1); \
  u32 pk = (u1 < u0) ? (u32)(2*h + 1) : (u32)(2*h); \
  if (pu < bc##c) { bc##c = pu; kc##c = pk; } }

__global__ __launch_bounds__(64, 1) void emd_greedy_kernel(
    const float* __restrict__ pred, const float* __restrict__ target,
    float* __restrict__ batch_sums) {
  const int b = blockIdx.x, lane = threadIdx.x;
  const float* p = pred + (size_t)b * NPTS * 3;
  const float* t = target + (size_t)b * NPTS * 3;
  __shared__ float4 pp[NPTS + 2];
  for (int i = lane; i < NPTS; i += 64) {
    float x = p[3 * i], y = p[3 * i + 1], z = p[3 * i + 2];
    pp[i] = make_float4(x, y, z, x * x + y * y + z * z);
  }
  if (lane < 2) pp[NPTS + lane] = make_float4(0.f, 0.f, 0.f, 0.f);
  const float* tb = t + (size_t)lane * 32 * 3;
  FOR16(LOADP)
  FOR16(DECLRU)
  u32 usedmask = 0;
  float sum = 0.f;
  __syncthreads();
  const v2f m2v = {-2.f, -2.f};
  v2f Xv, Yv, Zv, Qv;
  {
    float4 A = pp[0];
    Xv = (v2f){A.x, A.x}; Yv = (v2f){A.y, A.y};
    Zv = (v2f){A.z, A.z}; Qv = (v2f){A.w, A.w};
    FOR16(DIST)
  }
  for (int i = 0; i < NPTS; ++i) {
    float4 An = pp[i + 1];
    u32 bc0 = ~0u, bc1 = ~0u, bc2 = ~0u, bc3 = ~0u;
    u32 kc0 = 0, kc1 = 0, kc2 = 0, kc3 = 0;
    TOUR(0, 0)  TOUR(1, 0)  TOUR(2, 0)  TOUR(3, 0)
    TOUR(4, 1)  TOUR(5, 1)  TOUR(6, 1)  TOUR(7, 1)
    TOUR(8, 2)  TOUR(9, 2)  TOUR(10, 2) TOUR(11, 2)
    TOUR(12, 3) TOUR(13, 3) TOUR(14, 3) TOUR(15, 3)
    bool s01 = bc1 < bc0; u32 v01 = s01 ? bc1 : bc0; u32 i01 = s01 ? kc1 : kc0;
    bool s23 = bc3 < bc2; u32 v23 = s23 ? bc3 : bc2; u32 i23 = s23 ? kc3 : kc2;
    bool sf  = v23 < v01; u32 bu  = sf ? v23 : v01; u32 bk  = sf ? i23 : i01;
    Xv = (v2f){An.x, An.x}; Yv = (v2f){An.y, An.y};
    Zv = (v2f){An.z, An.z}; Qv = (v2f){An.w, An.w};
    FOR16(DIST)
    u32 m = bu;
    m = dpp_min<0xB1>(m); m = dpp_min<0x4E>(m);
    m = dpp_min<0x141>(m); m = dpp_min<0x140>(m);
    m = x16_min(m); m = x32_min(m);
    u64 mk = __ballot(bu == m);
    int first = __ffsll(mk) - 1;
    usedmask |= (lane == first) ? (1u << bk) : 0u;
    sum += sqrtf(fmaxf(__uint_as_float(m), 1e-12f));
  }
  if (lane == 0) batch_sums[b] = sum;
}

// ---------- finalize ----------
__global__ void emd_finalize_kernel(const float* __restrict__ batch_sums,
                                    float* __restrict__ out, int B) {
  float acc = 0.f;
  for (int b = 0; b < B; ++b) acc += batch_sums[b] / (float)NPTS;
  out[0] = acc / (float)B;
}

extern "C" void kernel_launch(void* const* d_in, const int* in_sizes, int n_in,
                              void* d_out, int out_size, void* d_ws, size_t ws_size,
                              hipStream_t stream) {
  const float* pred   = (const float*)d_in[0];
  const float* target = (const float*)d_in[1];
  float* out = (float*)d_out;
  const int B = in_sizes[0] / (NPTS * 3);

  const size_t need = 256 + (size_t)B * NPTS * TOPK * sizeof(u64);
  if (ws_size >= need) {
    float* bs = (float*)d_ws;
    u64* lists = (u64*)((char*)d_ws + 256);
    emd_topk_kernel<<<B * (NPTS / RPB), 64, 0, stream>>>(pred, target, lists);
    emd_seq_kernel<<<B, 64, 0, stream>>>(pred, target, lists, bs);
    emd_finalize_kernel<<<1, 1, 0, stream>>>(bs, out, B);
  } else {
    float* bs = (float*)d_ws;
    emd_greedy_kernel<<<B, 64, 0, stream>>>(pred, target, bs);
    emd_finalize_kernel<<<1, 1, 0, stream>>>(bs, out, B);
  }
}

// Round 13
// 408.427 us; speedup vs baseline: 1.9545x; 1.1287x over previous
//
#include <hip/hip_runtime.h>

#define NPTS 2048
#define TOPK 32
#define RPB  8        // rows per block in phase 1
#define MAINBLKS 30   // fixpoint blocks; tail handled densely
#define TAILROWS (NPTS - MAINBLKS * 64)  // 128

typedef float v2f __attribute__((ext_vector_type(2)));
typedef unsigned int u32;
typedef u32 v2u __attribute__((ext_vector_type(2)));
typedef unsigned long long u64;

// ---------- helpers ----------
static __device__ __forceinline__ u32 umin32(u32 a, u32 b) { return b < a ? b : a; }
static __device__ __forceinline__ u64 umin64(u64 a, u64 b) { return b < a ? b : a; }

template <int CTRL>
static __device__ __forceinline__ u32 dpp_min(u32 m) {
  return umin32(m, (u32)__builtin_amdgcn_mov_dpp((int)m, CTRL, 0xF, 0xF, true));
}
static __device__ __forceinline__ u32 x16_min(u32 m) {
#if __has_builtin(__builtin_amdgcn_permlane16_swap)
  auto r = __builtin_amdgcn_permlane16_swap((int)m, (int)m, false, false);
  return umin32(m, umin32((u32)r[0], (u32)r[1]));
#else
  return umin32(m, (u32)__builtin_amdgcn_ds_swizzle((int)m, 0x401F));
#endif
}
static __device__ __forceinline__ u32 x32_min(u32 m) {
#if __has_builtin(__builtin_amdgcn_permlane32_swap)
  auto r = __builtin_amdgcn_permlane32_swap((int)m, (int)m, false, false);
  return umin32(m, umin32((u32)r[0], (u32)r[1]));
#else
  return umin32(m, (u32)__shfl_xor((int)m, 32, 64));
#endif
}
static __device__ __forceinline__ u32 sext_bit(u32 mask, int c) {
#if __has_builtin(__builtin_amdgcn_sbfe)
  return (u32)__builtin_amdgcn_sbfe((int)mask, c, 1);
#else
  return (u32)(((int)(mask << (31 - c))) >> 31);
#endif
}

template <int CTRL>
static __device__ __forceinline__ u64 dpp_min64(u64 k) {
  unsigned lo = (unsigned)k, hi = (unsigned)(k >> 32);
  unsigned olo = (unsigned)__builtin_amdgcn_mov_dpp((int)lo, CTRL, 0xF, 0xF, true);
  unsigned ohi = (unsigned)__builtin_amdgcn_mov_dpp((int)hi, CTRL, 0xF, 0xF, true);
  return umin64(k, ((u64)ohi << 32) | olo);
}
static __device__ __forceinline__ u64 x16_min64(u64 k) {
  unsigned lo = (unsigned)k, hi = (unsigned)(k >> 32);
#if __has_builtin(__builtin_amdgcn_permlane16_swap)
  auto rlo = __builtin_amdgcn_permlane16_swap(lo, lo, false, false);
  auto rhi = __builtin_amdgcn_permlane16_swap(hi, hi, false, false);
  u64 a = ((u64)rhi[0] << 32) | rlo[0];
  u64 b = ((u64)rhi[1] << 32) | rlo[1];
  return umin64(k, umin64(a, b));
#else
  unsigned olo = (unsigned)__builtin_amdgcn_ds_swizzle((int)lo, 0x401F);
  unsigned ohi = (unsigned)__builtin_amdgcn_ds_swizzle((int)hi, 0x401F);
  return umin64(k, ((u64)ohi << 32) | olo);
#endif
}
static __device__ __forceinline__ u64 x32_min64(u64 k) {
  unsigned lo = (unsigned)k, hi = (unsigned)(k >> 32);
#if __has_builtin(__builtin_amdgcn_permlane32_swap)
  auto rlo = __builtin_amdgcn_permlane32_swap(lo, lo, false, false);
  auto rhi = __builtin_amdgcn_permlane32_swap(hi, hi, false, false);
  u64 a = ((u64)rhi[0] << 32) | rlo[0];
  u64 b = ((u64)rhi[1] << 32) | rlo[1];
  return umin64(k, umin64(a, b));
#else
  unsigned olo = (unsigned)__shfl_xor((int)lo, 32, 64);
  unsigned ohi = (unsigned)__shfl_xor((int)hi, 32, 64);
  return umin64(k, ((u64)ohi << 32) | olo);
#endif
}
static __device__ __forceinline__ u64 wave_min_u64(u64 k) {
  k = dpp_min64<0xB1>(k);
  k = dpp_min64<0x4E>(k);
  k = dpp_min64<0x141>(k);
  k = dpp_min64<0x140>(k);
  k = x16_min64(k);
  k = x32_min64(k);
  return k;  // wave-uniform
}

#define FOR16(M) M(0) M(1) M(2) M(3) M(4) M(5) M(6) M(7) \
                 M(8) M(9) M(10) M(11) M(12) M(13) M(14) M(15)

// Lane's 32 target columns in NAMED registers, as float2 pairs.
#define LOADP(h) \
  v2f TX##h, TY##h, TZ##h, TQ##h; \
  { float x0 = tb[6*h+0], y0 = tb[6*h+1], z0 = tb[6*h+2]; \
    float x1 = tb[6*h+3], y1 = tb[6*h+4], z1 = tb[6*h+5]; \
    TX##h = (v2f){x0, x1}; TY##h = (v2f){y0, y1}; TZ##h = (v2f){z0, z1}; \
    TQ##h = (v2f){x0*x0 + y0*y0 + z0*z0, x1*x1 + y1*y1 + z1*z1}; }

// ---------- phase 1: exact per-row sorted top-32, incremental tree ----------
#define DISTK(h) u64 KA##h, KB##h; { \
  v2f dot = __builtin_elementwise_fma(TX##h, Xv, \
              __builtin_elementwise_fma(TY##h, Yv, TZ##h * Zv)); \
  v2f dd  = __builtin_elementwise_fma(m2v, dot, TQ##h); \
  v2f d2  = Qv + dd; \
  float c0 = fmaxf(d2.x, 1e-12f), c1 = fmaxf(d2.y, 1e-12f); \
  KA##h = ((u64)(u32)__float_as_int(c0) << 32) | (u32)(base + 2*(h)); \
  KB##h = ((u64)(u32)__float_as_int(c1) << 32) | (u32)(base + 2*(h) + 1); }

#define G4(a, b, c, d) umin64(umin64(a, b), umin64(c, d))
#define ZG(c, KV, RL) case (c): KV = own ? ~0ULL : KV; goto RL;

__global__ __launch_bounds__(64, 2) void emd_topk_kernel(
    const float* __restrict__ pred, const float* __restrict__ target,
    u64* __restrict__ lists) {
  const int blk = blockIdx.x;
  const int b  = blk / (NPTS / RPB);
  const int r0 = (blk % (NPTS / RPB)) * RPB;
  const int lane = threadIdx.x;
  const float* p = pred + (size_t)b * NPTS * 3;
  const float* t = target + (size_t)b * NPTS * 3;

  const float* tb = t + (size_t)lane * 32 * 3;
  FOR16(LOADP)
  const int base = lane << 5;
  const v2f m2v = {-2.f, -2.f};

#pragma unroll 1
  for (int rr = 0; rr < RPB; ++rr) {
    const int i = r0 + rr;
    const float X = p[3 * i], Y = p[3 * i + 1], Z = p[3 * i + 2];
    const float Q = fmaf(X, X, fmaf(Y, Y, Z * Z));
    const v2f Xv = {X, X}, Yv = {Y, Y}, Zv = {Z, Z}, Qv = {Q, Q};
    FOR16(DISTK)

    u64 g0 = G4(KA0, KB0, KA1, KB1),   g1 = G4(KA2, KB2, KA3, KB3);
    u64 g2 = G4(KA4, KB4, KA5, KB5),   g3 = G4(KA6, KB6, KA7, KB7);
    u64 g4 = G4(KA8, KB8, KA9, KB9),   g5 = G4(KA10, KB10, KA11, KB11);
    u64 g6 = G4(KA12, KB12, KA13, KB13), g7 = G4(KA14, KB14, KA15, KB15);
    u64 h0 = umin64(g0, g1), h1 = umin64(g2, g3);
    u64 h2 = umin64(g4, g5), h3 = umin64(g6, g7);
    u64 q0 = umin64(h0, h1), q1 = umin64(h2, h3);
    u64 root = umin64(q0, q1);

    u64* out = lists + ((size_t)b * NPTS + i) * TOPK;
#pragma unroll 1
    for (int e = 0; e < TOPK; ++e) {
      u64 m = wave_min_u64(root);
      if (lane == 0) out[e] = m;
      if (e == TOPK - 1) break;
      const u32 col = (u32)m & (u32)(NPTS - 1);  // wave-uniform
      const bool own = (lane == (int)(col >> 5));
      const u32 k5 = col & 31u;
      switch (k5) {
        ZG(0,  KA0,  R0) ZG(1,  KB0,  R0) ZG(2,  KA1,  R0) ZG(3,  KB1,  R0)
        ZG(4,  KA2,  R1) ZG(5,  KB2,  R1) ZG(6,  KA3,  R1) ZG(7,  KB3,  R1)
        ZG(8,  KA4,  R2) ZG(9,  KB4,  R2) ZG(10, KA5,  R2) ZG(11, KB5,  R2)
        ZG(12, KA6,  R3) ZG(13, KB6,  R3) ZG(14, KA7,  R3) ZG(15, KB7,  R3)
        ZG(16, KA8,  R4) ZG(17, KB8,  R4) ZG(18, KA9,  R4) ZG(19, KB9,  R4)
        ZG(20, KA10, R5) ZG(21, KB10, R5) ZG(22, KA11, R5) ZG(23, KB11, R5)
        ZG(24, KA12, R6) ZG(25, KB12, R6) ZG(26, KA13, R6) ZG(27, KB13, R6)
        ZG(28, KA14, R7) ZG(29, KB14, R7) ZG(30, KA15, R7) ZG(31, KB15, R7)
        default: __builtin_unreachable();
      }
      R0: g0 = G4(KA0, KB0, KA1, KB1);     h0 = umin64(g0, g1); q0 = umin64(h0, h1); root = umin64(q0, q1); continue;
      R1: g1 = G4(KA2, KB2, KA3, KB3);     h0 = umin64(g0, g1); q0 = umin64(h0, h1); root = umin64(q0, q1); continue;
      R2: g2 = G4(KA4, KB4, KA5, KB5);     h1 = umin64(g2, g3); q0 = umin64(h0, h1); root = umin64(q0, q1); continue;
      R3: g3 = G4(KA6, KB6, KA7, KB7);     h1 = umin64(g2, g3); q0 = umin64(h0, h1); root = umin64(q0, q1); continue;
      R4: g4 = G4(KA8, KB8, KA9, KB9);     h2 = umin64(g4, g5); q1 = umin64(h2, h3); root = umin64(q0, q1); continue;
      R5: g5 = G4(KA10, KB10, KA11, KB11); h2 = umin64(g4, g5); q1 = umin64(h2, h3); root = umin64(q0, q1); continue;
      R6: g6 = G4(KA12, KB12, KA13, KB13); h3 = umin64(g6, g7); q1 = umin64(h2, h3); root = umin64(q0, q1); continue;
      R7: g7 = G4(KA14, KB14, KA15, KB15); h3 = umin64(g6, g7); q1 = umin64(h2, h3); root = umin64(q0, q1); continue;
    }
  }
}

// ---------- phase 2: iterative prefix-commit DA + dense register tail ----------
// Blocks 0..29: cascade fixpoint + iterative exhausted-row resolve (round 12,
// absmax 0). Blocks 30-31 (F = 128 free cols): dense tail — the 128 free
// columns live in 2 regs/lane; each of the last 128 rows is one u64 wave-min
// over the free set. Exact: same d2 formula, (d2,col) lex key = ref tie order.

#define LD16(M) M(0) M(1) M(2) M(3) M(4) M(5) M(6) M(7) \
                M(8) M(9) M(10) M(11) M(12) M(13) M(14) M(15)
#define DECLA(j) uint4 A##j;
#define LDA(j)   A##j = Lr[j];
// rank-major store: entry (rank k, row lane) at cl64[k*64+lane] (2-way, free)
#define WRC(j)   { cl64w[(2*(j)) * 64 + lane]     = ((u64)A##j.y << 32) | A##j.x; \
                   cl64w[(2*(j) + 1) * 64 + lane] = ((u64)A##j.w << 32) | A##j.z; }
#define FREEB(j) { \
    u32 c0 = A##j.x & 2047u, c1 = A##j.z & 2047u; \
    u32 w0 = sbm[c0 >> 5], w1 = sbm[c1 >> 5]; \
    alive |= ((~(w0 >> (c0 & 31u))) & 1u) << (2*(j)); \
    alive |= ((~(w1 >> (c1 & 31u))) & 1u) << (2*(j)+1); }

__global__ __launch_bounds__(64, 1) void emd_seq_kernel(
    const float* __restrict__ pred, const float* __restrict__ target,
    const u64* __restrict__ lists, float* __restrict__ batch_sums) {
  const int b = blockIdx.x, lane = threadIdx.x;
  const float* t = target + (size_t)b * NPTS * 3;
  const float* p = pred + (size_t)b * NPTS * 3;

  __shared__ float4 tt[NPTS];      // target coords (32 KB)
  __shared__ u64 cl64s[TOPK * 64]; // block candidates, rank-major (16 KB)
  __shared__ u32 claim[NPTS];      // column claims (8 KB)
  __shared__ u32 fl[NPTS];         // compact free list (8 KB)
  __shared__ u32 sbitmap[64];      // used-columns bitmap
  __shared__ float4 ppred[64];     // current block's pred rows
  __shared__ float4 tpred[TAILROWS];  // tail pred rows (2 KB)

  for (int j = lane; j < NPTS; j += 64) {
    float x = t[3 * j], y = t[3 * j + 1], z = t[3 * j + 2];
    tt[((j & 31) << 6) | ((j >> 5) ^ (j & 31))] =
        make_float4(x, y, z, fmaf(x, x, fmaf(y, y, z * z)));
  }
  sbitmap[lane] = 0u;
  __syncthreads();

  const u64* L = lists + (size_t)b * NPTS * TOPK;
  u64* cl64w = cl64s;
  const u64* cl64 = cl64s;
  volatile u32* sbm = sbitmap;
  volatile u32* vclaim = claim;
  float psum = 0.f;

  const uint4* Lr = (const uint4*)(L + (size_t)lane * TOPK);
  LD16(DECLA)
  LD16(LDA)

#pragma unroll 1
  for (int blk = 0; blk < MAINBLKS; ++blk) {
    LD16(WRC)
    u32 alive = 0u;
    LD16(FREEB)
    { const float* pr = p + (size_t)(blk * 64 + lane) * 3;
      float X = pr[0], Y = pr[1], Z = pr[2];
      ppred[lane] = make_float4(X, Y, Z, fmaf(X, X, fmaf(Y, Y, Z * Z))); }
    { int nrow = (blk + 1) * 64 + lane; nrow = nrow < NPTS ? nrow : NPTS - 1;
      Lr = (const uint4*)(L + (size_t)nrow * TOPK); }
    LD16(LDA)
#pragma unroll
    for (int k = 0; k < 32; ++k) claim[k * 64 + lane] = ~0u;

    bool committed = false;
    bool exh = (alive == 0u);
    u32 rank = 0, col = 0;
    u64 cur = 0;
    if (!exh) {
      rank = (u32)__ffs(alive) - 1u;
      cur = cl64[rank * 64 + lane];
      col = (u32)cur & 2047u;
      atomicMin(&claim[col], (u32)lane);
    }
    bool flBuilt = false;
    u32 F = 0;

    int oguard = 0;
#pragma unroll 1
    while (true) {
      // ---- cascade to fixpoint ----
      int guard = 0;
      while (true) {
        bool changed = false;
        if (!committed && !exh) {
          int g2 = 0;
          while (true) {
            u32 c = vclaim[col];
            if (c >= (u32)lane) break;  // we hold it
            alive &= ~(1u << rank);
            if (alive == 0u) { exh = true; break; }
            rank = (u32)__ffs(alive) - 1u;
            cur = cl64[rank * 64 + lane];
            col = (u32)cur & 2047u;
            atomicMin(&claim[col], (u32)lane);
            changed = true;
            if (++g2 > 33) break;
          }
        }
        if (__ballot(changed) == 0ULL) break;
        if (++guard > 3000) break;
      }

      u64 exbl = __ballot(exh && !committed);
      if (exbl == 0ULL) break;
      int rstar = __ffsll(exbl) - 1;

      if (!committed && !exh && lane < rstar) {
        atomicOr(&sbitmap[col >> 5], 1u << (col & 31u));
        psum += sqrtf(__uint_as_float((u32)(cur >> 32)));
        committed = true;
      }

      if (!flBuilt) {
        u32 fw = ~sbm[lane];
        u32 cnt = __popc(fw);
        u32 pfx = cnt;
#pragma unroll
        for (int d = 1; d < 64; d <<= 1) {
          u32 o = (u32)__shfl_up((int)pfx, d, 64);
          if (lane >= d) pfx += o;
        }
        F = (u32)__shfl((int)pfx, 63, 64);
        pfx -= cnt;
        while (fw) {
          int bpos = __ffs(fw) - 1;
          fw &= fw - 1u;
          fl[pfx++] = ((u32)lane << 5) + (u32)bpos;
        }
        flBuilt = true;
      }

      {
        float4 P4 = ppred[rstar];
        float X = P4.x, Y = P4.y, Z = P4.z, Q = P4.w;
        u64 mb = ~0ULL;
        for (u32 k = (u32)lane; k < F; k += 64) {
          u32 c = fl[k];
          u32 used = (sbm[c >> 5] >> (c & 31u)) & 1u;
          float4 c4 = tt[((c & 31u) << 6) | ((c >> 5) ^ (c & 31u))];
          float dot = fmaf(c4.x, X, fmaf(c4.y, Y, c4.z * Z));
          float d2 = Q + fmaf(-2.f, dot, c4.w);
          d2 = fmaxf(d2, 1e-12f);
          u64 kk = ((u64)(u32)__float_as_int(d2) << 32) | c;
          if (used) kk = ~0ULL;
          mb = umin64(mb, kk);
        }
        mb = wave_min_u64(mb);
        u32 cst = (u32)mb & 2047u;
        if (lane == rstar) {
          psum += sqrtf(__uint_as_float((u32)(mb >> 32)));
          committed = true;
          atomicOr(&sbitmap[cst >> 5], 1u << (cst & 31u));
          atomicMin(&claim[cst], (u32)rstar);
        }
      }
      if (++oguard > 66) break;
    }

    if (!committed) {
      atomicOr(&sbitmap[col >> 5], 1u << (col & 31u));
      psum += sqrtf(__uint_as_float((u32)(cur >> 32)));
    }
  }

  // ---- dense register tail: rows MAINBLKS*64 .. 2047 over F free cols ----
  {
    // compact the F (=128) free columns
    u32 fw = ~sbm[lane];
    u32 cnt = __popc(fw);
    u32 pfx = cnt;
#pragma unroll
    for (int d = 1; d < 64; d <<= 1) {
      u32 o = (u32)__shfl_up((int)pfx, d, 64);
      if (lane >= d) pfx += o;
    }
    u32 F = (u32)__shfl((int)pfx, 63, 64);
    pfx -= cnt;
    while (fw) {
      int bpos = __ffs(fw) - 1;
      fw &= fw - 1u;
      fl[pfx++] = ((u32)lane << 5) + (u32)bpos;
    }
    // stage tail pred rows
    { const float* pr = p + (size_t)(MAINBLKS * 64 + lane) * 3;
      float X = pr[0], Y = pr[1], Z = pr[2];
      tpred[lane] = make_float4(X, Y, Z, fmaf(X, X, fmaf(Y, Y, Z * Z))); }
    { const float* pr = p + (size_t)(MAINBLKS * 64 + 64 + lane) * 3;
      float X = pr[0], Y = pr[1], Z = pr[2];
      tpred[64 + lane] = make_float4(X, Y, Z, fmaf(X, X, fmaf(Y, Y, Z * Z))); }

    bool l0 = (u32)lane < F, l1 = (u32)(64 + lane) < F;
    u32 c0 = l0 ? fl[lane] : 0u;
    u32 c1 = l1 ? fl[64 + lane] : 0u;
    float4 t0 = tt[((c0 & 31u) << 6) | ((c0 >> 5) ^ (c0 & 31u))];
    float4 t1 = tt[((c1 & 31u) << 6) | ((c1 >> 5) ^ (c1 & 31u))];

#pragma unroll 1
    for (int r = 0; r < TAILROWS; ++r) {
      float4 P = tpred[r];
      float X = P.x, Y = P.y, Z = P.z, Q = P.w;
      float dot0 = fmaf(t0.x, X, fmaf(t0.y, Y, t0.z * Z));
      float d20 = fmaxf(Q + fmaf(-2.f, dot0, t0.w), 1e-12f);
      float dot1 = fmaf(t1.x, X, fmaf(t1.y, Y, t1.z * Z));
      float d21 = fmaxf(Q + fmaf(-2.f, dot1, t1.w), 1e-12f);
      u64 k0 = l0 ? (((u64)(u32)__float_as_int(d20) << 32) | c0) : ~0ULL;
      u64 k1 = l1 ? (((u64)(u32)__float_as_int(d21) << 32) | c1) : ~0ULL;
      u64 k = wave_min_u64(umin64(k0, k1));
      u32 wc = (u32)k & 2047u;
      l0 = l0 && (c0 != wc);
      l1 = l1 && (c1 != wc);
      if (lane == 0) psum += sqrtf(__uint_as_float((u32)(k >> 32)));
    }
  }

  float v = psum;
  v += __shfl_xor(v, 1, 64);
  v += __shfl_xor(v, 2, 64);
  v += __shfl_xor(v, 4, 64);
  v += __shfl_xor(v, 8, 64);
  v += __shfl_xor(v, 16, 64);
  v += __shfl_xor(v, 32, 64);
  if (lane == 0) batch_sums[b] = v;
}

// ---------- legacy single-kernel path (round-5, proven; ws-too-small) ----------
#define DECLRU(h) v2u RU##h;
#define DIST(h) { \
  v2f dot = __builtin_elementwise_fma(TX##h, Xv, \
              __builtin_elementwise_fma(TY##h, Yv, TZ##h * Zv)); \
  v2f dd  = __builtin_elementwise_fma(m2v, dot, TQ##h); \
  v2f d2  = Qv + dd; \
  RU##h = (v2u){(u32)__float_as_int(d2.x), (u32)__float_as_int(d2.y)}; }
#define TOUR(h, c) { \
  u32 u0 = RU##h.x | sext_bit(usedmask, 2*h); \
  u32 u1 = RU##h.y | sext_bit(usedmask, 2*h + 1); \
  u32 pu = umin32(u0, u1); \
  u32 pk = (u1 < u0) ? (u32)(2*h + 1) : (u32)(2*h); \
  if (pu < bc##c) { bc##c = pu; kc##c = pk; } }

__global__ __launch_bounds__(64, 1) void emd_greedy_kernel(
    const float* __restrict__ pred, const float* __restrict__ target,
    float* __restrict__ batch_sums) {
  const int b = blockIdx.x, lane = threadIdx.x;
  const float* p = pred + (size_t)b * NPTS * 3;
  const float* t = target + (size_t)b * NPTS * 3;
  __shared__ float4 pp[NPTS + 2];
  for (int i = lane; i < NPTS; i += 64) {
    float x = p[3 * i], y = p[3 * i + 1], z = p[3 * i + 2];
    pp[i] = make_float4(x, y, z, x * x + y * y + z * z);
  }
  if (lane < 2) pp[NPTS + lane] = make_float4(0.f, 0.f, 0.f, 0.f);
  const float* tb = t + (size_t)lane * 32 * 3;
  FOR16(LOADP)
  FOR16(DECLRU)
  u32 usedmask = 0;
  float sum = 0.f;
  __syncthreads();
  const v2f m2v = {-2.f, -2.f};
  v2f Xv, Yv, Zv, Qv;
  {
    float4 A = pp[0];
    Xv = (v2f){A.x, A.x}; Yv = (v2f){A.y, A.y};
    Zv = (v2f){A.z, A.z}; Qv = (v2f){A.w, A.w};
    FOR16(DIST)
  }
  for (int i = 0; i < NPTS; ++i) {
    float4 An = pp[i + 1];
    u32 bc0 = ~0u, bc1 = ~0u, bc2 = ~0u, bc3 = ~0u;
    u32 kc0 = 0, kc1 = 0, kc2 = 0, kc3 = 0;
    TOUR(0, 0)  TOUR(1, 0)  TOUR(2, 0)  TOUR(3, 0)
    TOUR(4, 1)  TOUR(5, 1)  TOUR(6, 1)  TOUR(7, 1)
    TOUR(8, 2)  TOUR(9, 2)  TOUR(10, 2) TOUR(11, 2)
    TOUR(12, 3) TOUR(13, 3) TOUR(14, 3) TOUR(15, 3)
    bool s01 = bc1 < bc0; u32 v01 = s01 ? bc1 : bc0; u32 i01 = s01 ? kc1 : kc0;
    bool s23 = bc3 < bc2; u32 v23 = s23 ? bc3 : bc2; u32 i23 = s23 ? kc3 : kc2;
    bool sf  = v23 < v01; u32 bu  = sf ? v23 : v01; u32 bk  = sf ? i23 : i01;
    Xv = (v2f){An.x, An.x}; Yv = (v2f){An.y, An.y};
    Zv = (v2f){An.z, An.z}; Qv = (v2f){An.w, An.w};
    FOR16(DIST)
    u32 m = bu;
    m = dpp_min<0xB1>(m); m = dpp_min<0x4E>(m);
    m = dpp_min<0x141>(m); m = dpp_min<0x140>(m);
    m = x16_min(m); m = x32_min(m);
    u64 mk = __ballot(bu == m);
    int first = __ffsll(mk) - 1;
    usedmask |= (lane == first) ? (1u << bk) : 0u;
    sum += sqrtf(fmaxf(__uint_as_float(m), 1e-12f));
  }
  if (lane == 0) batch_sums[b] = sum;
}

// ---------- finalize ----------
__global__ void emd_finalize_kernel(const float* __restrict__ batch_sums,
                                    float* __restrict__ out, int B) {
  float acc = 0.f;
  for (int b = 0; b < B; ++b) acc += batch_sums[b] / (float)NPTS;
  out[0] = acc / (float)B;
}

extern "C" void kernel_launch(void* const* d_in, const int* in_sizes, int n_in,
                              void* d_out, int out_size, void* d_ws, size_t ws_size,
                              hipStream_t stream) {
  const float* pred   = (const float*)d_in[0];
  const float* target = (const float*)d_in[1];
  float* out = (float*)d_out;
  const int B = in_sizes[0] / (NPTS * 3);

  const size_t need = 256 + (size_t)B * NPTS * TOPK * sizeof(u64);
  if (ws_size >= need) {
    float* bs = (float*)d_ws;
    u64* lists = (u64*)((char*)d_ws + 256);
    emd_topk_kernel<<<B * (NPTS / RPB), 64, 0, stream>>>(pred, target, lists);
    emd_seq_kernel<<<B, 64, 0, stream>>>(pred, target, lists, bs);
    emd_finalize_kernel<<<1, 1, 0, stream>>>(bs, out, B);
  } else {
    float* bs = (float*)d_ws;
    emd_greedy_kernel<<<B, 64, 0, stream>>>(pred, target, bs);
    emd_finalize_kernel<<<1, 1, 0, stream>>>(bs, out, B);
  }
}

// Round 14
// 395.815 us; speedup vs baseline: 2.0168x; 1.0319x over previous
//
#include <hip/hip_runtime.h>

#define NPTS 2048
#define TOPK 32
#define RPB  8        // rows per block in phase 1
#define MAINBLKS 30   // fixpoint blocks; tail handled densely
#define TAILROWS (NPTS - MAINBLKS * 64)  // 128

typedef float v2f __attribute__((ext_vector_type(2)));
typedef unsigned int u32;
typedef u32 v2u __attribute__((ext_vector_type(2)));
typedef unsigned long long u64;

// ---------- helpers ----------
static __device__ __forceinline__ u32 umin32(u32 a, u32 b) { return b < a ? b : a; }
static __device__ __forceinline__ u64 umin64(u64 a, u64 b) { return b < a ? b : a; }

template <int CTRL>
static __device__ __forceinline__ u32 dpp_min(u32 m) {
  return umin32(m, (u32)__builtin_amdgcn_mov_dpp((int)m, CTRL, 0xF, 0xF, true));
}
static __device__ __forceinline__ u32 x16_min(u32 m) {
#if __has_builtin(__builtin_amdgcn_permlane16_swap)
  auto r = __builtin_amdgcn_permlane16_swap((int)m, (int)m, false, false);
  return umin32(m, umin32((u32)r[0], (u32)r[1]));
#else
  return umin32(m, (u32)__builtin_amdgcn_ds_swizzle((int)m, 0x401F));
#endif
}
static __device__ __forceinline__ u32 x32_min(u32 m) {
#if __has_builtin(__builtin_amdgcn_permlane32_swap)
  auto r = __builtin_amdgcn_permlane32_swap((int)m, (int)m, false, false);
  return umin32(m, umin32((u32)r[0], (u32)r[1]));
#else
  return umin32(m, (u32)__shfl_xor((int)m, 32, 64));
#endif
}
static __device__ __forceinline__ u32 sext_bit(u32 mask, int c) {
#if __has_builtin(__builtin_amdgcn_sbfe)
  return (u32)__builtin_amdgcn_sbfe((int)mask, c, 1);
#else
  return (u32)(((int)(mask << (31 - c))) >> 31);
#endif
}

template <int CTRL>
static __device__ __forceinline__ u64 dpp_min64(u64 k) {
  unsigned lo = (unsigned)k, hi = (unsigned)(k >> 32);
  unsigned olo = (unsigned)__builtin_amdgcn_mov_dpp((int)lo, CTRL, 0xF, 0xF, true);
  unsigned ohi = (unsigned)__builtin_amdgcn_mov_dpp((int)hi, CTRL, 0xF, 0xF, true);
  return umin64(k, ((u64)ohi << 32) | olo);
}
static __device__ __forceinline__ u64 x16_min64(u64 k) {
  unsigned lo = (unsigned)k, hi = (unsigned)(k >> 32);
#if __has_builtin(__builtin_amdgcn_permlane16_swap)
  auto rlo = __builtin_amdgcn_permlane16_swap(lo, lo, false, false);
  auto rhi = __builtin_amdgcn_permlane16_swap(hi, hi, false, false);
  u64 a = ((u64)rhi[0] << 32) | rlo[0];
  u64 b = ((u64)rhi[1] << 32) | rlo[1];
  return umin64(k, umin64(a, b));
#else
  unsigned olo = (unsigned)__builtin_amdgcn_ds_swizzle((int)lo, 0x401F);
  unsigned ohi = (unsigned)__builtin_amdgcn_ds_swizzle((int)hi, 0x401F);
  return umin64(k, ((u64)ohi << 32) | olo);
#endif
}
static __device__ __forceinline__ u64 x32_min64(u64 k) {
  unsigned lo = (unsigned)k, hi = (unsigned)(k >> 32);
#if __has_builtin(__builtin_amdgcn_permlane32_swap)
  auto rlo = __builtin_amdgcn_permlane32_swap(lo, lo, false, false);
  auto rhi = __builtin_amdgcn_permlane32_swap(hi, hi, false, false);
  u64 a = ((u64)rhi[0] << 32) | rlo[0];
  u64 b = ((u64)rhi[1] << 32) | rlo[1];
  return umin64(k, umin64(a, b));
#else
  unsigned olo = (unsigned)__shfl_xor((int)lo, 32, 64);
  unsigned ohi = (unsigned)__shfl_xor((int)hi, 32, 64);
  return umin64(k, ((u64)ohi << 32) | olo);
#endif
}
static __device__ __forceinline__ u64 wave_min_u64(u64 k) {
  k = dpp_min64<0xB1>(k);
  k = dpp_min64<0x4E>(k);
  k = dpp_min64<0x141>(k);
  k = dpp_min64<0x140>(k);
  k = x16_min64(k);
  k = x32_min64(k);
  return k;  // wave-uniform
}

#define FOR16(M) M(0) M(1) M(2) M(3) M(4) M(5) M(6) M(7) \
                 M(8) M(9) M(10) M(11) M(12) M(13) M(14) M(15)

// Lane's 32 target columns in NAMED registers, as float2 pairs.
#define LOADP(h) \
  v2f TX##h, TY##h, TZ##h, TQ##h; \
  { float x0 = tb[6*h+0], y0 = tb[6*h+1], z0 = tb[6*h+2]; \
    float x1 = tb[6*h+3], y1 = tb[6*h+4], z1 = tb[6*h+5]; \
    TX##h = (v2f){x0, x1}; TY##h = (v2f){y0, y1}; TZ##h = (v2f){z0, z1}; \
    TQ##h = (v2f){x0*x0 + y0*y0 + z0*z0, x1*x1 + y1*y1 + z1*z1}; }

// ---------- phase 1: exact per-row sorted top-32, incremental tree ----------
#define DISTK(h) u64 KA##h, KB##h; { \
  v2f dot = __builtin_elementwise_fma(TX##h, Xv, \
              __builtin_elementwise_fma(TY##h, Yv, TZ##h * Zv)); \
  v2f dd  = __builtin_elementwise_fma(m2v, dot, TQ##h); \
  v2f d2  = Qv + dd; \
  float c0 = fmaxf(d2.x, 1e-12f), c1 = fmaxf(d2.y, 1e-12f); \
  KA##h = ((u64)(u32)__float_as_int(c0) << 32) | (u32)(base + 2*(h)); \
  KB##h = ((u64)(u32)__float_as_int(c1) << 32) | (u32)(base + 2*(h) + 1); }

#define G4(a, b, c, d) umin64(umin64(a, b), umin64(c, d))
#define ZG(c, KV, RL) case (c): KV = own ? ~0ULL : KV; goto RL;

__global__ __launch_bounds__(64, 2) void emd_topk_kernel(
    const float* __restrict__ pred, const float* __restrict__ target,
    u64* __restrict__ lists) {
  const int blk = blockIdx.x;
  const int b  = blk / (NPTS / RPB);
  const int r0 = (blk % (NPTS / RPB)) * RPB;
  const int lane = threadIdx.x;
  const float* p = pred + (size_t)b * NPTS * 3;
  const float* t = target + (size_t)b * NPTS * 3;

  const float* tb = t + (size_t)lane * 32 * 3;
  FOR16(LOADP)
  const int base = lane << 5;
  const v2f m2v = {-2.f, -2.f};

#pragma unroll 1
  for (int rr = 0; rr < RPB; ++rr) {
    const int i = r0 + rr;
    const float X = p[3 * i], Y = p[3 * i + 1], Z = p[3 * i + 2];
    const float Q = fmaf(X, X, fmaf(Y, Y, Z * Z));
    const v2f Xv = {X, X}, Yv = {Y, Y}, Zv = {Z, Z}, Qv = {Q, Q};
    FOR16(DISTK)

    u64 g0 = G4(KA0, KB0, KA1, KB1),   g1 = G4(KA2, KB2, KA3, KB3);
    u64 g2 = G4(KA4, KB4, KA5, KB5),   g3 = G4(KA6, KB6, KA7, KB7);
    u64 g4 = G4(KA8, KB8, KA9, KB9),   g5 = G4(KA10, KB10, KA11, KB11);
    u64 g6 = G4(KA12, KB12, KA13, KB13), g7 = G4(KA14, KB14, KA15, KB15);
    u64 h0 = umin64(g0, g1), h1 = umin64(g2, g3);
    u64 h2 = umin64(g4, g5), h3 = umin64(g6, g7);
    u64 q0 = umin64(h0, h1), q1 = umin64(h2, h3);
    u64 root = umin64(q0, q1);

    u64* out = lists + ((size_t)b * NPTS + i) * TOPK;
#pragma unroll 1
    for (int e = 0; e < TOPK; ++e) {
      u64 m = wave_min_u64(root);
      if (lane == 0) out[e] = m;
      if (e == TOPK - 1) break;
      const u32 col = (u32)m & (u32)(NPTS - 1);  // wave-uniform
      const bool own = (lane == (int)(col >> 5));
      const u32 k5 = col & 31u;
      switch (k5) {
        ZG(0,  KA0,  R0) ZG(1,  KB0,  R0) ZG(2,  KA1,  R0) ZG(3,  KB1,  R0)
        ZG(4,  KA2,  R1) ZG(5,  KB2,  R1) ZG(6,  KA3,  R1) ZG(7,  KB3,  R1)
        ZG(8,  KA4,  R2) ZG(9,  KB4,  R2) ZG(10, KA5,  R2) ZG(11, KB5,  R2)
        ZG(12, KA6,  R3) ZG(13, KB6,  R3) ZG(14, KA7,  R3) ZG(15, KB7,  R3)
        ZG(16, KA8,  R4) ZG(17, KB8,  R4) ZG(18, KA9,  R4) ZG(19, KB9,  R4)
        ZG(20, KA10, R5) ZG(21, KB10, R5) ZG(22, KA11, R5) ZG(23, KB11, R5)
        ZG(24, KA12, R6) ZG(25, KB12, R6) ZG(26, KA13, R6) ZG(27, KB13, R6)
        ZG(28, KA14, R7) ZG(29, KB14, R7) ZG(30, KA15, R7) ZG(31, KB15, R7)
        default: __builtin_unreachable();
      }
      R0: g0 = G4(KA0, KB0, KA1, KB1);     h0 = umin64(g0, g1); q0 = umin64(h0, h1); root = umin64(q0, q1); continue;
      R1: g1 = G4(KA2, KB2, KA3, KB3);     h0 = umin64(g0, g1); q0 = umin64(h0, h1); root = umin64(q0, q1); continue;
      R2: g2 = G4(KA4, KB4, KA5, KB5);     h1 = umin64(g2, g3); q0 = umin64(h0, h1); root = umin64(q0, q1); continue;
      R3: g3 = G4(KA6, KB6, KA7, KB7);     h1 = umin64(g2, g3); q0 = umin64(h0, h1); root = umin64(q0, q1); continue;
      R4: g4 = G4(KA8, KB8, KA9, KB9);     h2 = umin64(g4, g5); q1 = umin64(h2, h3); root = umin64(q0, q1); continue;
      R5: g5 = G4(KA10, KB10, KA11, KB11); h2 = umin64(g4, g5); q1 = umin64(h2, h3); root = umin64(q0, q1); continue;
      R6: g6 = G4(KA12, KB12, KA13, KB13); h3 = umin64(g6, g7); q1 = umin64(h2, h3); root = umin64(q0, q1); continue;
      R7: g7 = G4(KA14, KB14, KA15, KB15); h3 = umin64(g6, g7); q1 = umin64(h2, h3); root = umin64(q0, q1); continue;
    }
  }
}

// ---------- phase 2: iterative prefix-commit DA, cheap no-displacement
// resolve, dense register tail ----------
// Blocks 0..29: cascade once; then per exhausted row: free-search -> commit;
// re-cascade ONLY if the chosen column was claimed by a stable row (rare).
// Blocks 30-31: dense tail (round 13, absmax 0).

#define LD16(M) M(0) M(1) M(2) M(3) M(4) M(5) M(6) M(7) \
                M(8) M(9) M(10) M(11) M(12) M(13) M(14) M(15)
#define DECLA(j) uint4 A##j;
#define LDA(j)   A##j = Lr[j];
// rank-major store: entry (rank k, row lane) at cl64[k*64+lane] (2-way, free)
#define WRC(j)   { cl64w[(2*(j)) * 64 + lane]     = ((u64)A##j.y << 32) | A##j.x; \
                   cl64w[(2*(j) + 1) * 64 + lane] = ((u64)A##j.w << 32) | A##j.z; }
#define FREEB(j) { \
    u32 c0 = A##j.x & 2047u, c1 = A##j.z & 2047u; \
    u32 w0 = sbm[c0 >> 5], w1 = sbm[c1 >> 5]; \
    alive |= ((~(w0 >> (c0 & 31u))) & 1u) << (2*(j)); \
    alive |= ((~(w1 >> (c1 & 31u))) & 1u) << (2*(j)+1); }

// Ballot cascade: uncommitted non-exhausted lanes chase claims to fixpoint.
#define CASCADE() { \
    int guard_ = 0; \
    while (true) { \
      bool changed_ = false; \
      if (!committed && !exh) { \
        int g2_ = 0; \
        while (true) { \
          u32 c_ = vclaim[col]; \
          if (c_ >= (u32)lane) break; \
          alive &= ~(1u << rank); \
          if (alive == 0u) { exh = true; break; } \
          rank = (u32)__ffs(alive) - 1u; \
          cur = cl64[rank * 64 + lane]; \
          col = (u32)cur & 2047u; \
          atomicMin(&claim[col], (u32)lane); \
          changed_ = true; \
          if (++g2_ > 33) break; \
        } \
      } \
      if (__ballot(changed_) == 0ULL) break; \
      if (++guard_ > 3000) break; \
    } }

__global__ __launch_bounds__(64, 1) void emd_seq_kernel(
    const float* __restrict__ pred, const float* __restrict__ target,
    const u64* __restrict__ lists, float* __restrict__ batch_sums) {
  const int b = blockIdx.x, lane = threadIdx.x;
  const float* t = target + (size_t)b * NPTS * 3;
  const float* p = pred + (size_t)b * NPTS * 3;

  __shared__ float4 tt[NPTS];      // target coords (32 KB)
  __shared__ u64 cl64s[TOPK * 64]; // block candidates, rank-major (16 KB)
  __shared__ u32 claim[NPTS];      // column claims (8 KB)
  __shared__ u32 fl[NPTS];         // compact free list (8 KB)
  __shared__ u32 sbitmap[64];      // used-columns bitmap
  __shared__ float4 ppred[64];     // current block's pred rows
  __shared__ float4 tpred[TAILROWS];  // tail pred rows (2 KB)

  for (int j = lane; j < NPTS; j += 64) {
    float x = t[3 * j], y = t[3 * j + 1], z = t[3 * j + 2];
    tt[((j & 31) << 6) | ((j >> 5) ^ (j & 31))] =
        make_float4(x, y, z, fmaf(x, x, fmaf(y, y, z * z)));
  }
  sbitmap[lane] = 0u;
  __syncthreads();

  const u64* L = lists + (size_t)b * NPTS * TOPK;
  u64* cl64w = cl64s;
  const u64* cl64 = cl64s;
  volatile u32* sbm = sbitmap;
  volatile u32* vclaim = claim;
  float psum = 0.f;

  const uint4* Lr = (const uint4*)(L + (size_t)lane * TOPK);
  LD16(DECLA)
  LD16(LDA)

#pragma unroll 1
  for (int blk = 0; blk < MAINBLKS; ++blk) {
    LD16(WRC)
    u32 alive = 0u;
    LD16(FREEB)
    { const float* pr = p + (size_t)(blk * 64 + lane) * 3;
      float X = pr[0], Y = pr[1], Z = pr[2];
      ppred[lane] = make_float4(X, Y, Z, fmaf(X, X, fmaf(Y, Y, Z * Z))); }
    { int nrow = (blk + 1) * 64 + lane; nrow = nrow < NPTS ? nrow : NPTS - 1;
      Lr = (const uint4*)(L + (size_t)nrow * TOPK); }
    LD16(LDA)
#pragma unroll
    for (int k = 0; k < 32; ++k) claim[k * 64 + lane] = ~0u;

    bool committed = false;
    bool exh = (alive == 0u);
    u32 rank = 0, col = 0;
    u64 cur = 0;
    if (!exh) {
      rank = (u32)__ffs(alive) - 1u;
      cur = cl64[rank * 64 + lane];
      col = (u32)cur & 2047u;
      atomicMin(&claim[col], (u32)lane);
    }
    CASCADE()

    bool flBuilt = false;
    u32 F = 0;
    int oguard = 0;
#pragma unroll 1
    while (true) {
      u64 exbl = __ballot(exh && !committed);
      if (exbl == 0ULL) break;
      int rstar = __ffsll(exbl) - 1;

      // progressive prefix commit of stable rows below rstar
      if (!committed && !exh && lane < rstar) {
        atomicOr(&sbitmap[col >> 5], 1u << (col & 31u));
        psum += sqrtf(__uint_as_float((u32)(cur >> 32)));
        committed = true;
      }

      if (!flBuilt) {
        u32 fw = ~sbm[lane];
        u32 cnt = __popc(fw);
        u32 pfx = cnt;
#pragma unroll
        for (int d = 1; d < 64; d <<= 1) {
          u32 o = (u32)__shfl_up((int)pfx, d, 64);
          if (lane >= d) pfx += o;
        }
        F = (u32)__shfl((int)pfx, 63, 64);
        pfx -= cnt;
        while (fw) {
          int bpos = __ffs(fw) - 1;
          fw &= fw - 1u;
          fl[pfx++] = ((u32)lane << 5) + (u32)bpos;
        }
        flBuilt = true;
      }

      // exact resolve of row rstar: min over live free columns
      u32 cst;
      {
        float4 P4 = ppred[rstar];
        float X = P4.x, Y = P4.y, Z = P4.z, Q = P4.w;
        u64 mb = ~0ULL;
        for (u32 k = (u32)lane; k < F; k += 64) {
          u32 c = fl[k];
          u32 used = (sbm[c >> 5] >> (c & 31u)) & 1u;
          float4 c4 = tt[((c & 31u) << 6) | ((c >> 5) ^ (c & 31u))];
          float dot = fmaf(c4.x, X, fmaf(c4.y, Y, c4.z * Z));
          float d2 = Q + fmaf(-2.f, dot, c4.w);
          d2 = fmaxf(d2, 1e-12f);
          u64 kk = ((u64)(u32)__float_as_int(d2) << 32) | c;
          if (used) kk = ~0ULL;
          mb = umin64(mb, kk);
        }
        mb = wave_min_u64(mb);
        cst = (u32)mb & 2047u;
        if (lane == rstar) {
          psum += sqrtf(__uint_as_float((u32)(mb >> 32)));
          committed = true;
        }
      }
      // was cst claimed by a stable (uncommitted) row? (broadcast read,
      // BEFORE the claim injection below)
      u32 prev = vclaim[cst];
      if (lane == rstar) {
        atomicOr(&sbitmap[cst >> 5], 1u << (cst & 31u));
        atomicMin(&claim[cst], (u32)rstar);
      }
      if (prev != ~0u) {
        // displaced holder (prev > rstar, uncommitted) re-chases
        CASCADE()
      }
      if (++oguard > 80) break;
    }

    // commit all remaining stable rows
    if (!committed) {
      atomicOr(&sbitmap[col >> 5], 1u << (col & 31u));
      psum += sqrtf(__uint_as_float((u32)(cur >> 32)));
    }
  }

  // ---- dense register tail: rows MAINBLKS*64 .. 2047 over F free cols ----
  {
    u32 fw = ~sbm[lane];
    u32 cnt = __popc(fw);
    u32 pfx = cnt;
#pragma unroll
    for (int d = 1; d < 64; d <<= 1) {
      u32 o = (u32)__shfl_up((int)pfx, d, 64);
      if (lane >= d) pfx += o;
    }
    u32 F = (u32)__shfl((int)pfx, 63, 64);
    pfx -= cnt;
    while (fw) {
      int bpos = __ffs(fw) - 1;
      fw &= fw - 1u;
      fl[pfx++] = ((u32)lane << 5) + (u32)bpos;
    }
    { const float* pr = p + (size_t)(MAINBLKS * 64 + lane) * 3;
      float X = pr[0], Y = pr[1], Z = pr[2];
      tpred[lane] = make_float4(X, Y, Z, fmaf(X, X, fmaf(Y, Y, Z * Z))); }
    { const float* pr = p + (size_t)(MAINBLKS * 64 + 64 + lane) * 3;
      float X = pr[0], Y = pr[1], Z = pr[2];
      tpred[64 + lane] = make_float4(X, Y, Z, fmaf(X, X, fmaf(Y, Y, Z * Z))); }

    bool l0 = (u32)lane < F, l1 = (u32)(64 + lane) < F;
    u32 c0 = l0 ? fl[lane] : 0u;
    u32 c1 = l1 ? fl[64 + lane] : 0u;
    float4 t0 = tt[((c0 & 31u) << 6) | ((c0 >> 5) ^ (c0 & 31u))];
    float4 t1 = tt[((c1 & 31u) << 6) | ((c1 >> 5) ^ (c1 & 31u))];

#pragma unroll 1
    for (int r = 0; r < TAILROWS; ++r) {
      float4 P = tpred[r];
      float X = P.x, Y = P.y, Z = P.z, Q = P.w;
      float dot0 = fmaf(t0.x, X, fmaf(t0.y, Y, t0.z * Z));
      float d20 = fmaxf(Q + fmaf(-2.f, dot0, t0.w), 1e-12f);
      float dot1 = fmaf(t1.x, X, fmaf(t1.y, Y, t1.z * Z));
      float d21 = fmaxf(Q + fmaf(-2.f, dot1, t1.w), 1e-12f);
      u64 k0 = l0 ? (((u64)(u32)__float_as_int(d20) << 32) | c0) : ~0ULL;
      u64 k1 = l1 ? (((u64)(u32)__float_as_int(d21) << 32) | c1) : ~0ULL;
      u64 k = wave_min_u64(umin64(k0, k1));
      u32 wc = (u32)k & 2047u;
      l0 = l0 && (c0 != wc);
      l1 = l1 && (c1 != wc);
      if (lane == 0) psum += sqrtf(__uint_as_float((u32)(k >> 32)));
    }
  }

  float v = psum;
  v += __shfl_xor(v, 1, 64);
  v += __shfl_xor(v, 2, 64);
  v += __shfl_xor(v, 4, 64);
  v += __shfl_xor(v, 8, 64);
  v += __shfl_xor(v, 16, 64);
  v += __shfl_xor(v, 32, 64);
  if (lane == 0) batch_sums[b] = v;
}

// ---------- legacy single-kernel path (round-5, proven; ws-too-small) ----------
#define DECLRU(h) v2u RU##h;
#define DIST(h) { \
  v2f dot = __builtin_elementwise_fma(TX##h, Xv, \
              __builtin_elementwise_fma(TY##h, Yv, TZ##h * Zv)); \
  v2f dd  = __builtin_elementwise_fma(m2v, dot, TQ##h); \
  v2f d2  = Qv + dd; \
  RU##h = (v2u){(u32)__float_as_int(d2.x), (u32)__float_as_int(d2.y)}; }
#define TOUR(h, c) { \
  u32 u0 = RU##h.x | sext_bit(usedmask, 2*h); \
  u32 u1 = RU##h.y | sext_bit(usedmask, 2*h + 1); \
  u32 pu = umin32(u0, u1); \
  u32 pk = (u1 < u0) ? (u32)(2*h + 1) : (u32)(2*h); \
  if (pu < bc##c) { bc##c = pu; kc##c = pk; } }

__global__ __launch_bounds__(64, 1) void emd_greedy_kernel(
    const float* __restrict__ pred, const float* __restrict__ target,
    float* __restrict__ batch_sums) {
  const int b = blockIdx.x, lane = threadIdx.x;
  const float* p = pred + (size_t)b * NPTS * 3;
  const float* t = target + (size_t)b * NPTS * 3;
  __shared__ float4 pp[NPTS + 2];
  for (int i = lane; i < NPTS; i += 64) {
    float x = p[3 * i], y = p[3 * i + 1], z = p[3 * i + 2];
    pp[i] = make_float4(x, y, z, x * x + y * y + z * z);
  }
  if (lane < 2) pp[NPTS + lane] = make_float4(0.f, 0.f, 0.f, 0.f);
  const float* tb = t + (size_t)lane * 32 * 3;
  FOR16(LOADP)
  FOR16(DECLRU)
  u32 usedmask = 0;
  float sum = 0.f;
  __syncthreads();
  const v2f m2v = {-2.f, -2.f};
  v2f Xv, Yv, Zv, Qv;
  {
    float4 A = pp[0];
    Xv = (v2f){A.x, A.x}; Yv = (v2f){A.y, A.y};
    Zv = (v2f){A.z, A.z}; Qv = (v2f){A.w, A.w};
    FOR16(DIST)
  }
  for (int i = 0; i < NPTS; ++i) {
    float4 An = pp[i + 1];
    u32 bc0 = ~0u, bc1 = ~0u, bc2 = ~0u, bc3 = ~0u;
    u32 kc0 = 0, kc1 = 0, kc2 = 0, kc3 = 0;
    TOUR(0, 0)  TOUR(1, 0)  TOUR(2, 0)  TOUR(3, 0)
    TOUR(4, 1)  TOUR(5, 1)  TOUR(6, 1)  TOUR(7, 1)
    TOUR(8, 2)  TOUR(9, 2)  TOUR(10, 2) TOUR(11, 2)
    TOUR(12, 3) TOUR(13, 3) TOUR(14, 3) TOUR(15, 3)
    bool s01 = bc1 < bc0; u32 v01 = s01 ? bc1 : bc0; u32 i01 = s01 ? kc1 : kc0;
    bool s23 = bc3 < bc2; u32 v23 = s23 ? bc3 : bc2; u32 i23 = s23 ? kc3 : kc2;
    bool sf  = v23 < v01; u32 bu  = sf ? v23 : v01; u32 bk  = sf ? i23 : i01;
    Xv = (v2f){An.x, An.x}; Yv = (v2f){An.y, An.y};
    Zv = (v2f){An.z, An.z}; Qv = (v2f){An.w, An.w};
    FOR16(DIST)
    u32 m = bu;
    m = dpp_min<0xB1>(m); m = dpp_min<0x4E>(m);
    m = dpp_min<0x141>(m); m = dpp_min<0x140>(m);
    m = x16_min(m); m = x32_min(m);
    u64 mk = __ballot(bu == m);
    int first = __ffsll(mk) - 1;
    usedmask |= (lane == first) ? (1u << bk) : 0u;
    sum += sqrtf(fmaxf(__uint_as_float(m), 1e-12f));
  }
  if (lane == 0) batch_sums[b] = sum;
}

// ---------- finalize ----------
__global__ void emd_finalize_kernel(const float* __restrict__ batch_sums,
                                    float* __restrict__ out, int B) {
  float acc = 0.f;
  for (int b = 0; b < B; ++b) acc += batch_sums[b] / (float)NPTS;
  out[0] = acc / (float)B;
}

extern "C" void kernel_launch(void* const* d_in, const int* in_sizes, int n_in,
                              void* d_out, int out_size, void* d_ws, size_t ws_size,
                              hipStream_t stream) {
  const float* pred   = (const float*)d_in[0];
  const float* target = (const float*)d_in[1];
  float* out = (float*)d_out;
  const int B = in_sizes[0] / (NPTS * 3);

  const size_t need = 256 + (size_t)B * NPTS * TOPK * sizeof(u64);
  if (ws_size >= need) {
    float* bs = (float*)d_ws;
    u64* lists = (u64*)((char*)d_ws + 256);
    emd_topk_kernel<<<B * (NPTS / RPB), 64, 0, stream>>>(pred, target, lists);
    emd_seq_kernel<<<B, 64, 0, stream>>>(pred, target, lists, bs);
    emd_finalize_kernel<<<1, 1, 0, stream>>>(bs, out, B);
  } else {
    float* bs = (float*)d_ws;
    emd_greedy_kernel<<<B, 64, 0, stream>>>(pred, target, bs);
    emd_finalize_kernel<<<1, 1, 0, stream>>>(bs, out, B);
  }
}